// Round 1
// baseline (2095.223 us; speedup 1.0000x reference)
//
#include <hip/hip_runtime.h>

typedef __attribute__((ext_vector_type(8))) short bf16x8;
typedef __attribute__((ext_vector_type(4))) float f32x4;
typedef unsigned short u16;

#define D_MODEL 1024
#define SEQ 512
#define BATCH 4
#define NH 16
#define FF 4096
#define NLAYER 6

__device__ __forceinline__ u16 f2bf(float f) {
  unsigned int u = __float_as_uint(f);
  u += 0x7fffu + ((u >> 16) & 1u);
  return (u16)(u >> 16);
}

// ---------------- positional encoding: h = x + pe ----------------
__global__ __launch_bounds__(256) void posenc_k(const float* __restrict__ x, float* __restrict__ h) {
  int row = blockIdx.x;           // b*512 + s
  int s = row & (SEQ - 1);
  int t = threadIdx.x;
  float4 v = *(const float4*)(x + (size_t)row * D_MODEL + t * 4);
  float r[4] = {v.x, v.y, v.z, v.w};
#pragma unroll
  for (int j = 0; j < 4; ++j) {
    int d = t * 4 + j;
    int p = d >> 1;
    // 10000^(-2p/1024) = exp2(-2p/1024 * log2(10000))
    float ang = (float)s * exp2f((float)p * (-2.0f / 1024.0f) * 13.287712379549449f);
    r[j] += (d & 1) ? cosf(ang) : sinf(ang);
  }
  float4 o = {r[0], r[1], r[2], r[3]};
  *(float4*)(h + (size_t)row * D_MODEL + t * 4) = o;
}

// ---------------- GEMM: C = act(A@B + bias)*scale ----------------
// A: MxK row-major (fp32 or bf16), B: KxN row-major fp32 (converted to bf16 on the fly)
// 128x128 tile, BK=32, 4 waves (2x2), each wave 64x64 via 4x4 16x16x32 mfma
#define BMt 128
#define BNt 128
#define PADK 40   // LDS K-stride (bf16 elems): 80B rows -> 16B aligned, conflict-reducing

template <int ABF, int OBF, int RELU>
__device__ __forceinline__ void gemm_body(const void* __restrict__ Av, const float* __restrict__ B,
                                          const float* __restrict__ bias, void* __restrict__ Cv,
                                          int M, int N, int K, float scale, int bx, int by) {
  __shared__ u16 As[BMt * PADK];
  __shared__ u16 Bs[BNt * PADK];
  const int t = threadIdx.x;
  const int lane = t & 63, wave = t >> 6;
  const int wm = wave >> 1, wn = wave & 1;
  const int lrow = lane & 15, lgrp = lane >> 4;
  const int m0 = by * BMt, n0 = bx * BNt;

  f32x4 acc[4][4];
#pragma unroll
  for (int i = 0; i < 4; ++i)
#pragma unroll
    for (int j = 0; j < 4; ++j) acc[i][j] = (f32x4){0.f, 0.f, 0.f, 0.f};

  const int ar0 = t >> 3, ac4 = t & 7;   // A staging: 4 rows (ar0+32k), quad ac4
  const int bn_ = t & 127, bkg = t >> 7; // B staging: col n, k-halves

  for (int k0 = 0; k0 < K; k0 += 32) {
    // stage A (128x32) -> As[m][k]
#pragma unroll
    for (int rr = 0; rr < 4; ++rr) {
      int r = ar0 + rr * 32;
      if (ABF) {
        ushort4 v = *(const ushort4*)((const u16*)Av + (size_t)(m0 + r) * K + k0 + ac4 * 4);
        *(ushort4*)(&As[r * PADK + ac4 * 4]) = v;
      } else {
        float4 v = *(const float4*)((const float*)Av + (size_t)(m0 + r) * K + k0 + ac4 * 4);
        ushort4 w;
        w.x = f2bf(v.x); w.y = f2bf(v.y); w.z = f2bf(v.z); w.w = f2bf(v.w);
        *(ushort4*)(&As[r * PADK + ac4 * 4]) = w;
      }
    }
    // stage B transposed -> Bs[n][k]; global reads coalesced along n
    {
      const float* bp = B + (size_t)(k0 + bkg * 16) * N + n0 + bn_;
      u16 tmp[16];
#pragma unroll
      for (int i = 0; i < 16; ++i) tmp[i] = f2bf(bp[(size_t)i * N]);
#pragma unroll
      for (int c = 0; c < 4; ++c) {
        ushort4 w;
        w.x = tmp[c * 4]; w.y = tmp[c * 4 + 1]; w.z = tmp[c * 4 + 2]; w.w = tmp[c * 4 + 3];
        *(ushort4*)(&Bs[bn_ * PADK + bkg * 16 + c * 4]) = w;
      }
    }
    __syncthreads();
    bf16x8 af[4], bfr[4];
#pragma unroll
    for (int i = 0; i < 4; ++i) {
      af[i] = *(const bf16x8*)(&As[(wm * 64 + i * 16 + lrow) * PADK + lgrp * 8]);
      bfr[i] = *(const bf16x8*)(&Bs[(wn * 64 + i * 16 + lrow) * PADK + lgrp * 8]);
    }
#pragma unroll
    for (int i = 0; i < 4; ++i)
#pragma unroll
      for (int j = 0; j < 4; ++j)
        acc[i][j] = __builtin_amdgcn_mfma_f32_16x16x32_bf16(af[i], bfr[j], acc[i][j], 0, 0, 0);
    __syncthreads();
  }

#pragma unroll
  for (int j = 0; j < 4; ++j) {
    int col = n0 + wn * 64 + j * 16 + lrow;
    float bv = bias[col];
#pragma unroll
    for (int i = 0; i < 4; ++i) {
      int rowb = m0 + wm * 64 + i * 16 + lgrp * 4;
#pragma unroll
      for (int r = 0; r < 4; ++r) {
        float v = (acc[i][j][r] + bv) * scale;
        if (RELU) v = fmaxf(v, 0.f);
        if (OBF)
          ((u16*)Cv)[(size_t)(rowb + r) * N + col] = f2bf(v);
        else
          ((float*)Cv)[(size_t)(rowb + r) * N + col] = v;
      }
    }
  }
}

template <int ABF, int OBF, int RELU>
__global__ __launch_bounds__(256) void gemm_k(const void* __restrict__ A, const float* __restrict__ B,
                                              const float* __restrict__ bias, void* __restrict__ C,
                                              int M, int N, int K, float scale) {
  gemm_body<ABF, OBF, RELU>(A, B, bias, C, M, N, K, scale, blockIdx.x, blockIdx.y);
}

// fused Q/K/V projection: z selects weight/bias/output; q pre-scaled by 1/sqrt(depth)
__global__ __launch_bounds__(256) void qkv_k(const float* __restrict__ A,
                                             const float* w0, const float* w1, const float* w2,
                                             const float* b0, const float* b1, const float* b2,
                                             u16* o0, u16* o1, u16* o2) {
  int z = blockIdx.z;
  const float* W = (z == 0) ? w0 : (z == 1) ? w1 : w2;
  const float* bb = (z == 0) ? b0 : (z == 1) ? b1 : b2;
  u16* O = (z == 0) ? o0 : (z == 1) ? o1 : o2;
  float scale = (z == 0) ? 0.125f : 1.0f;
  gemm_body<0, 1, 0>(A, W, bb, O, 2048, 1024, 1024, scale, blockIdx.x, blockIdx.y);
}

// ---------------- V transpose: vt[(b*16+h)*64+d][s] = v[(b*512+s)][h*64+d] ----------------
__global__ __launch_bounds__(256) void vtrans_k(const u16* __restrict__ v, u16* __restrict__ vt) {
  __shared__ u16 tile[32][33];
  const int bx = blockIdx.x, by = blockIdx.y, b = blockIdx.z;
  const int tx = threadIdx.x & 31, ty = threadIdx.x >> 5;
#pragma unroll
  for (int i = 0; i < 32; i += 8) {
    int sidx = bx * 32 + ty + i, d = by * 32 + tx;
    tile[ty + i][tx] = v[(size_t)(b * SEQ + sidx) * D_MODEL + d];
  }
  __syncthreads();
#pragma unroll
  for (int i = 0; i < 32; i += 8) {
    int d = by * 32 + ty + i, sidx = bx * 32 + tx;
    vt[(size_t)(b * D_MODEL + d) * SEQ + sidx] = tile[tx][ty + i];
  }
}

// ---------------- fused flash attention ----------------
// grid (4 q-blocks, B*H); block 256 = 4 waves, wave owns 32 q-rows. KV tile 64.
#define KPAD 72

__global__ __launch_bounds__(256) void attn_k(const u16* __restrict__ q, const u16* __restrict__ k,
                                              const u16* __restrict__ vt, const float* __restrict__ mask,
                                              float* __restrict__ o) {
  __shared__ u16 Ks[64 * KPAD];
  __shared__ u16 Vs[64 * KPAD];
  __shared__ u16 Ps[128 * KPAD];
  const int t = threadIdx.x;
  const int lane = t & 63, wave = t >> 6;
  const int lrow = lane & 15, lgrp = lane >> 4;
  const int qb = blockIdx.x;
  const int bh = blockIdx.y;
  const int b = bh >> 4, hh = bh & 15;

  bf16x8 qf[2][2];
  const int qrow0 = qb * 128 + wave * 32;
#pragma unroll
  for (int mt = 0; mt < 2; ++mt)
#pragma unroll
    for (int kk = 0; kk < 2; ++kk)
      qf[mt][kk] = *(const bf16x8*)(q + (size_t)(b * SEQ + qrow0 + mt * 16 + lrow) * D_MODEL +
                                    hh * 64 + kk * 32 + lgrp * 8);

  float mreg[2][4], lsum[2][4];
  f32x4 oacc[2][4];
#pragma unroll
  for (int mt = 0; mt < 2; ++mt)
#pragma unroll
    for (int r = 0; r < 4; ++r) { mreg[mt][r] = -1e30f; lsum[mt][r] = 0.f; }
#pragma unroll
  for (int mt = 0; mt < 2; ++mt)
#pragma unroll
    for (int dn = 0; dn < 4; ++dn) oacc[mt][dn] = (f32x4){0.f, 0.f, 0.f, 0.f};

  const int sr = t >> 3, sc = t & 7;
  for (int it = 0; it < 8; ++it) {
    const int kv0 = it * 64;
#pragma unroll
    for (int half = 0; half < 2; ++half) {
      int r = sr + half * 32;
      uint4 kv4 = *(const uint4*)(k + (size_t)(b * SEQ + kv0 + r) * D_MODEL + hh * 64 + sc * 8);
      *(uint4*)(&Ks[r * KPAD + sc * 8]) = kv4;
      uint4 vv4 = *(const uint4*)(vt + (size_t)(bh * 64 + r) * SEQ + kv0 + sc * 8);
      *(uint4*)(&Vs[r * KPAD + sc * 8]) = vv4;
    }
    __syncthreads();

    f32x4 s[2][4];
#pragma unroll
    for (int mt = 0; mt < 2; ++mt)
#pragma unroll
      for (int nt = 0; nt < 4; ++nt) s[mt][nt] = (f32x4){0.f, 0.f, 0.f, 0.f};
#pragma unroll
    for (int nt = 0; nt < 4; ++nt)
#pragma unroll
      for (int kk = 0; kk < 2; ++kk) {
        bf16x8 kf = *(const bf16x8*)(&Ks[(nt * 16 + lrow) * KPAD + kk * 32 + lgrp * 8]);
#pragma unroll
        for (int mt = 0; mt < 2; ++mt)
          s[mt][nt] = __builtin_amdgcn_mfma_f32_16x16x32_bf16(qf[mt][kk], kf, s[mt][nt], 0, 0, 0);
      }
    float mv[4];
#pragma unroll
    for (int nt = 0; nt < 4; ++nt) mv[nt] = mask[b * SEQ + kv0 + nt * 16 + lrow] * -1e9f;
#pragma unroll
    for (int mt = 0; mt < 2; ++mt)
#pragma unroll
      for (int nt = 0; nt < 4; ++nt)
#pragma unroll
        for (int r = 0; r < 4; ++r) s[mt][nt][r] = s[mt][nt][r] + mv[nt];

#pragma unroll
    for (int mt = 0; mt < 2; ++mt)
#pragma unroll
      for (int r = 0; r < 4; ++r) {
        float mx = fmaxf(fmaxf(s[mt][0][r], s[mt][1][r]), fmaxf(s[mt][2][r], s[mt][3][r]));
        mx = fmaxf(mx, __shfl_xor(mx, 1));
        mx = fmaxf(mx, __shfl_xor(mx, 2));
        mx = fmaxf(mx, __shfl_xor(mx, 4));
        mx = fmaxf(mx, __shfl_xor(mx, 8));
        float mnew = fmaxf(mreg[mt][r], mx);
        float corr = __expf(mreg[mt][r] - mnew);
        mreg[mt][r] = mnew;
        float p0 = __expf(s[mt][0][r] - mnew);
        float p1 = __expf(s[mt][1][r] - mnew);
        float p2 = __expf(s[mt][2][r] - mnew);
        float p3 = __expf(s[mt][3][r] - mnew);
        float rs = p0 + p1 + p2 + p3;
        rs += __shfl_xor(rs, 1);
        rs += __shfl_xor(rs, 2);
        rs += __shfl_xor(rs, 4);
        rs += __shfl_xor(rs, 8);
        lsum[mt][r] = lsum[mt][r] * corr + rs;
#pragma unroll
        for (int dn = 0; dn < 4; ++dn) oacc[mt][dn][r] = oacc[mt][dn][r] * corr;
        int prow = wave * 32 + mt * 16 + lgrp * 4 + r;
        Ps[prow * KPAD + 0 + lrow] = f2bf(p0);
        Ps[prow * KPAD + 16 + lrow] = f2bf(p1);
        Ps[prow * KPAD + 32 + lrow] = f2bf(p2);
        Ps[prow * KPAD + 48 + lrow] = f2bf(p3);
      }
    __syncthreads();
#pragma unroll
    for (int kk = 0; kk < 2; ++kk) {
      bf16x8 pf[2];
      pf[0] = *(const bf16x8*)(&Ps[(wave * 32 + 0 + lrow) * KPAD + kk * 32 + lgrp * 8]);
      pf[1] = *(const bf16x8*)(&Ps[(wave * 32 + 16 + lrow) * KPAD + kk * 32 + lgrp * 8]);
#pragma unroll
      for (int dn = 0; dn < 4; ++dn) {
        bf16x8 vf = *(const bf16x8*)(&Vs[(dn * 16 + lrow) * KPAD + kk * 32 + lgrp * 8]);
        oacc[0][dn] = __builtin_amdgcn_mfma_f32_16x16x32_bf16(pf[0], vf, oacc[0][dn], 0, 0, 0);
        oacc[1][dn] = __builtin_amdgcn_mfma_f32_16x16x32_bf16(pf[1], vf, oacc[1][dn], 0, 0, 0);
      }
    }
    __syncthreads();
  }
#pragma unroll
  for (int mt = 0; mt < 2; ++mt)
#pragma unroll
    for (int dn = 0; dn < 4; ++dn)
#pragma unroll
      for (int r = 0; r < 4; ++r) {
        int qrow = qrow0 + mt * 16 + lgrp * 4 + r;
        o[(size_t)(b * SEQ + qrow) * D_MODEL + hh * 64 + dn * 16 + lrow] =
            oacc[mt][dn][r] / lsum[mt][r];
      }
}

// ---------------- fused residual add + LayerNorm ----------------
__global__ __launch_bounds__(256) void ln_k(const float* __restrict__ a, const float* __restrict__ bres,
                                            const float* __restrict__ g, const float* __restrict__ be,
                                            float* __restrict__ out) {
  __shared__ float red[8];
  const int row = blockIdx.x, t = threadIdx.x;
  float4 va = *(const float4*)(a + (size_t)row * D_MODEL + t * 4);
  float4 vb = *(const float4*)(bres + (size_t)row * D_MODEL + t * 4);
  float x0 = va.x + vb.x, x1 = va.y + vb.y, x2 = va.z + vb.z, x3 = va.w + vb.w;
  float s = x0 + x1 + x2 + x3;
  float s2 = x0 * x0 + x1 * x1 + x2 * x2 + x3 * x3;
#pragma unroll
  for (int off = 1; off < 64; off <<= 1) {
    s += __shfl_xor(s, off);
    s2 += __shfl_xor(s2, off);
  }
  const int wave = t >> 6, lane = t & 63;
  if (lane == 0) { red[wave] = s; red[4 + wave] = s2; }
  __syncthreads();
  s = red[0] + red[1] + red[2] + red[3];
  s2 = red[4] + red[5] + red[6] + red[7];
  float mean = s * (1.f / D_MODEL);
  float var = s2 * (1.f / D_MODEL) - mean * mean;
  float inv = rsqrtf(var + 1e-6f);
  float4 vg = *(const float4*)(g + t * 4);
  float4 ve = *(const float4*)(be + t * 4);
  float4 r;
  r.x = (x0 - mean) * inv * vg.x + ve.x;
  r.y = (x1 - mean) * inv * vg.y + ve.y;
  r.z = (x2 - mean) * inv * vg.z + ve.z;
  r.w = (x3 - mean) * inv * vg.w + ve.w;
  *(float4*)(out + (size_t)row * D_MODEL + t * 4) = r;
}

// ---------------- launch ----------------
extern "C" void kernel_launch(void* const* d_in, const int* in_sizes, int n_in,
                              void* d_out, int out_size, void* d_ws, size_t ws_size,
                              hipStream_t stream) {
  const float* x = (const float*)d_in[0];
  const float* mask = (const float*)d_in[1];
  const float* Wq = (const float*)d_in[2];
  const float* bq = (const float*)d_in[3];
  const float* Wk = (const float*)d_in[4];
  const float* bk = (const float*)d_in[5];
  const float* Wv = (const float*)d_in[6];
  const float* bv = (const float*)d_in[7];
  const float* Wo = (const float*)d_in[8];
  const float* bo = (const float*)d_in[9];
  const float* W1 = (const float*)d_in[10];
  const float* b1 = (const float*)d_in[11];
  const float* W2 = (const float*)d_in[12];
  const float* b2 = (const float*)d_in[13];
  const float* g1 = (const float*)d_in[14];
  const float* be1 = (const float*)d_in[15];
  const float* g2 = (const float*)d_in[16];
  const float* be2 = (const float*)d_in[17];
  float* out = (float*)d_out;

  const size_t NTOK = (size_t)BATCH * SEQ;  // 2048
  const size_t ACT = NTOK * D_MODEL;        // 2M elems
  char* w = (char*)d_ws;
  float* h = (float*)w;   w += ACT * 4;
  float* h1 = (float*)w;  w += ACT * 4;
  float* ob = (float*)w;  w += ACT * 4;   // attn out, then FFN2 out
  float* op = (float*)w;  w += ACT * 4;   // o-projection out
  u16* qb_ = (u16*)w;     w += ACT * 2;
  u16* kb_ = (u16*)w;     w += ACT * 2;
  u16* vb_ = (u16*)w;     w += ACT * 2;
  u16* vt_ = (u16*)w;     w += ACT * 2;
  u16* tb_ = (u16*)w;     w += NTOK * FF * 2;

  posenc_k<<<(int)NTOK, 256, 0, stream>>>(x, h);
  for (int l = 0; l < NLAYER; ++l) {
    const float* wq = Wq + (size_t)l * D_MODEL * D_MODEL;
    const float* wk = Wk + (size_t)l * D_MODEL * D_MODEL;
    const float* wv = Wv + (size_t)l * D_MODEL * D_MODEL;
    const float* wo = Wo + (size_t)l * D_MODEL * D_MODEL;
    const float* w1 = W1 + (size_t)l * D_MODEL * FF;
    const float* w2 = W2 + (size_t)l * FF * D_MODEL;
    const float* bql = bq + (size_t)l * D_MODEL;
    const float* bkl = bk + (size_t)l * D_MODEL;
    const float* bvl = bv + (size_t)l * D_MODEL;
    const float* bol = bo + (size_t)l * D_MODEL;
    const float* b1l = b1 + (size_t)l * FF;
    const float* b2l = b2 + (size_t)l * D_MODEL;
    const float* g1l = g1 + (size_t)l * D_MODEL;
    const float* be1l = be1 + (size_t)l * D_MODEL;
    const float* g2l = g2 + (size_t)l * D_MODEL;
    const float* be2l = be2 + (size_t)l * D_MODEL;

    qkv_k<<<dim3(8, 16, 3), 256, 0, stream>>>(h, wq, wk, wv, bql, bkl, bvl, qb_, kb_, vb_);
    vtrans_k<<<dim3(16, 32, 4), 256, 0, stream>>>(vb_, vt_);
    attn_k<<<dim3(4, 64), 256, 0, stream>>>(qb_, kb_, vt_, mask, ob);
    gemm_k<0, 0, 0><<<dim3(8, 16), 256, 0, stream>>>(ob, wo, bol, op, 2048, 1024, 1024, 1.f);
    ln_k<<<(int)NTOK, 256, 0, stream>>>(h, op, g1l, be1l, h1);
    gemm_k<0, 1, 1><<<dim3(32, 16), 256, 0, stream>>>(h1, w1, b1l, tb_, 2048, 4096, 1024, 1.f);
    gemm_k<1, 0, 0><<<dim3(8, 16), 256, 0, stream>>>(tb_, w2, b2l, ob, 2048, 1024, 4096, 1.f);
    ln_k<<<(int)NTOK, 256, 0, stream>>>(h1, ob, g2l, be2l, (l == NLAYER - 1) ? out : h);
  }
}

// Round 3
// 1336.737 us; speedup vs baseline: 1.5674x; 1.5674x over previous
//
#include <hip/hip_runtime.h>

typedef __attribute__((ext_vector_type(8))) short bf16x8;
typedef __attribute__((ext_vector_type(4))) float f32x4;
typedef unsigned short u16;

#define D_MODEL 1024
#define SEQ 512
#define BATCH 4
#define NH 16
#define FF 4096
#define NLAYER 6

__device__ __forceinline__ u16 f2bf(float f) {
  unsigned int u = __float_as_uint(f);
  u += 0x7fffu + ((u >> 16) & 1u);
  return (u16)(u >> 16);
}

__device__ __forceinline__ void gload16(const void* g, void* lds) {
  __builtin_amdgcn_global_load_lds((const __attribute__((address_space(1))) void*)g,
                                   (__attribute__((address_space(3))) void*)lds, 16, 0, 0);
}

// ---------------- positional encoding: h = x + pe (f32 + bf16 outputs) ----------------
__global__ __launch_bounds__(256) void posenc_k(const float* __restrict__ x, float* __restrict__ h,
                                                u16* __restrict__ hb) {
  int row = blockIdx.x;  // b*512 + s
  int s = row & (SEQ - 1);
  int t = threadIdx.x;
  float4 v = *(const float4*)(x + (size_t)row * D_MODEL + t * 4);
  float r[4] = {v.x, v.y, v.z, v.w};
#pragma unroll
  for (int j = 0; j < 4; ++j) {
    int d = t * 4 + j;
    int p = d >> 1;
    float ang = (float)s * exp2f((float)p * (-2.0f / 1024.0f) * 13.287712379549449f);
    r[j] += (d & 1) ? cosf(ang) : sinf(ang);
  }
  float4 o = {r[0], r[1], r[2], r[3]};
  *(float4*)(h + (size_t)row * D_MODEL + t * 4) = o;
  ushort4 ob;
  ob.x = f2bf(r[0]); ob.y = f2bf(r[1]); ob.z = f2bf(r[2]); ob.w = f2bf(r[3]);
  *(ushort4*)(hb + (size_t)row * D_MODEL + t * 4) = ob;
}

// ---------------- weight transpose+convert: W[K][N] f32 -> Wt[N][K] bf16 (scaled) ----------------
#define TP 40  // padded k-stride in tile (u16): 80B rows, 16B aligned
__global__ __launch_bounds__(256) void wconv_k(const float* __restrict__ W, u16* __restrict__ Wt,
                                               int K, int N, float scale) {
  __shared__ u16 tile[32 * TP];
  const int t = threadIdx.x;
  const int kb = blockIdx.y * 32, nb = blockIdx.x * 32;
#pragma unroll
  for (int j = 0; j < 4; ++j) {
    int idx = t + j * 256;
    int k = idx >> 5, n = idx & 31;
    tile[n * TP + k] = f2bf(W[(size_t)(kb + k) * N + nb + n] * scale);
  }
  __syncthreads();
  if (t < 128) {
    int n = t >> 2, kv = t & 3;
    uint4 v = *(const uint4*)&tile[n * TP + kv * 8];
    *(uint4*)&Wt[(size_t)(nb + n) * K + kb + kv * 8] = v;
  }
}

// qkv bias concat (scale folded for q)
__global__ __launch_bounds__(256) void bqkv_k(const float* bq, const float* bk, const float* bv,
                                              float* bqkv) {
  int i = blockIdx.x * 256 + threadIdx.x;
  float v = (i < 1024) ? bq[i] * 0.125f : (i < 2048 ? bk[i - 1024] : bv[i - 2048]);
  bqkv[i] = v;
}

// ---------------- m97-style GEMM: C = act(A@Bt^T + bias) ----------------
// A [2048][K] bf16, Bt [N][K] bf16. BM=128, BK=32, BN template (128 or 64).
// 4 waves 2x2; global_load_lds dwordx4 staging, linear LDS, ds_read_b128 frags.
template <int BN, int OBF, int RELU>
__global__ __launch_bounds__(256) void gemm_bt(const u16* __restrict__ A, const u16* __restrict__ Bt,
                                               const float* __restrict__ bias, void* __restrict__ Cv,
                                               int N, int K) {
  constexpr int WN = BN / 2;   // 64 or 32
  constexpr int NR = WN / 16;  // 4 or 2
  __shared__ u16 As[128 * 32];
  __shared__ u16 Bs[BN * 32];
  const int t = threadIdx.x, lane = t & 63, wave = t >> 6;
  const int wm = wave >> 1, wn = wave & 1;
  const int lrow = lane & 15, lgrp = lane >> 4;
  const int m0 = blockIdx.y * 128, n0 = blockIdx.x * BN;

  f32x4 acc[4][NR];
#pragma unroll
  for (int i = 0; i < 4; ++i)
#pragma unroll
    for (int j = 0; j < NR; ++j) acc[i][j] = (f32x4){0.f, 0.f, 0.f, 0.f};

  const u16* Ag = A + (size_t)m0 * K;
  const u16* Bg = Bt + (size_t)n0 * K;

  for (int k0 = 0; k0 < K; k0 += 32) {
    // A tile: 128x32 bf16 = 8KB, 2 rounds/wave of 1KB
#pragma unroll
    for (int r = 0; r < 2; ++r) {
      int ebase = (wave * 2 + r) * 512;          // u16 index of wave-round base
      int e = ebase + lane * 8;                  // this lane's element
      int row = e >> 5, kc = e & 31;
      gload16(Ag + (size_t)row * K + k0 + kc, &As[ebase]);
    }
    // B tile: BN x 32 = BN*64B, BN/64 rounds/wave
#pragma unroll
    for (int r = 0; r < BN / 64; ++r) {
      int ebase = (wave * (BN / 64) + r) * 512;
      int e = ebase + lane * 8;
      int row = e >> 5, kc = e & 31;
      gload16(Bg + (size_t)row * K + k0 + kc, &Bs[ebase]);
    }
    __syncthreads();
    bf16x8 af[4], bfr[NR];
#pragma unroll
    for (int i = 0; i < 4; ++i)
      af[i] = *(const bf16x8*)&As[(wm * 64 + i * 16 + lrow) * 32 + lgrp * 8];
#pragma unroll
    for (int j = 0; j < NR; ++j)
      bfr[j] = *(const bf16x8*)&Bs[(wn * WN + j * 16 + lrow) * 32 + lgrp * 8];
#pragma unroll
    for (int i = 0; i < 4; ++i)
#pragma unroll
      for (int j = 0; j < NR; ++j)
        acc[i][j] = __builtin_amdgcn_mfma_f32_16x16x32_bf16(af[i], bfr[j], acc[i][j], 0, 0, 0);
    __syncthreads();
  }

#pragma unroll
  for (int j = 0; j < NR; ++j) {
    int col = n0 + wn * WN + j * 16 + lrow;
    float bv = bias[col];
#pragma unroll
    for (int i = 0; i < 4; ++i) {
      int rowb = m0 + wm * 64 + i * 16 + lgrp * 4;
#pragma unroll
      for (int r = 0; r < 4; ++r) {
        float v = acc[i][j][r] + bv;
        if (RELU) v = fmaxf(v, 0.f);
        if (OBF)
          ((u16*)Cv)[(size_t)(rowb + r) * N + col] = f2bf(v);
        else
          ((float*)Cv)[(size_t)(rowb + r) * N + col] = v;
      }
    }
  }
}

// ---------------- V transpose from fused qkv: vt[(b*16+h)*64+d][s] ----------------
__global__ __launch_bounds__(256) void vtrans_k(const u16* __restrict__ qkv, u16* __restrict__ vt) {
  __shared__ u16 tile[32][33];
  const int bx = blockIdx.x, by = blockIdx.y, b = blockIdx.z;
  const int tx = threadIdx.x & 31, ty = threadIdx.x >> 5;
#pragma unroll
  for (int i = 0; i < 32; i += 8) {
    int sidx = bx * 32 + ty + i, d = by * 32 + tx;
    tile[ty + i][tx] = qkv[(size_t)(b * SEQ + sidx) * 3072 + 2048 + d];
  }
  __syncthreads();
#pragma unroll
  for (int i = 0; i < 32; i += 8) {
    int d = by * 32 + ty + i, sidx = bx * 32 + tx;
    vt[(size_t)(b * D_MODEL + d) * SEQ + sidx] = tile[tx][ty + i];
  }
}

// ---------------- fused flash attention (reads fused qkv, writes bf16) ----------------
#define KPAD 72
__global__ __launch_bounds__(256) void attn_k(const u16* __restrict__ qkv, const u16* __restrict__ vt,
                                              const float* __restrict__ mask, u16* __restrict__ o) {
  __shared__ u16 Ks[64 * KPAD];
  __shared__ u16 Vs[64 * KPAD];
  __shared__ u16 Ps[128 * KPAD];
  const int t = threadIdx.x;
  const int lane = t & 63, wave = t >> 6;
  const int lrow = lane & 15, lgrp = lane >> 4;
  const int qb = blockIdx.x;
  const int bh = blockIdx.y;
  const int b = bh >> 4, hh = bh & 15;

  bf16x8 qf[2][2];
  const int qrow0 = qb * 128 + wave * 32;
#pragma unroll
  for (int mt = 0; mt < 2; ++mt)
#pragma unroll
    for (int kk = 0; kk < 2; ++kk)
      qf[mt][kk] = *(const bf16x8*)(qkv + (size_t)(b * SEQ + qrow0 + mt * 16 + lrow) * 3072 +
                                    hh * 64 + kk * 32 + lgrp * 8);

  float mreg[2][4], lsum[2][4];
  f32x4 oacc[2][4];
#pragma unroll
  for (int mt = 0; mt < 2; ++mt)
#pragma unroll
    for (int r = 0; r < 4; ++r) { mreg[mt][r] = -1e30f; lsum[mt][r] = 0.f; }
#pragma unroll
  for (int mt = 0; mt < 2; ++mt)
#pragma unroll
    for (int dn = 0; dn < 4; ++dn) oacc[mt][dn] = (f32x4){0.f, 0.f, 0.f, 0.f};

  const int sr = t >> 3, sc = t & 7;
  for (int it = 0; it < 8; ++it) {
    const int kv0 = it * 64;
#pragma unroll
    for (int half = 0; half < 2; ++half) {
      int r = sr + half * 32;
      uint4 kv4 = *(const uint4*)(qkv + (size_t)(b * SEQ + kv0 + r) * 3072 + 1024 + hh * 64 + sc * 8);
      *(uint4*)(&Ks[r * KPAD + sc * 8]) = kv4;
      uint4 vv4 = *(const uint4*)(vt + (size_t)(bh * 64 + r) * SEQ + kv0 + sc * 8);
      *(uint4*)(&Vs[r * KPAD + sc * 8]) = vv4;
    }
    __syncthreads();

    f32x4 s[2][4];
#pragma unroll
    for (int mt = 0; mt < 2; ++mt)
#pragma unroll
      for (int nt = 0; nt < 4; ++nt) s[mt][nt] = (f32x4){0.f, 0.f, 0.f, 0.f};
#pragma unroll
    for (int nt = 0; nt < 4; ++nt)
#pragma unroll
      for (int kk = 0; kk < 2; ++kk) {
        bf16x8 kf = *(const bf16x8*)(&Ks[(nt * 16 + lrow) * KPAD + kk * 32 + lgrp * 8]);
#pragma unroll
        for (int mt = 0; mt < 2; ++mt)
          s[mt][nt] = __builtin_amdgcn_mfma_f32_16x16x32_bf16(qf[mt][kk], kf, s[mt][nt], 0, 0, 0);
      }
    float mv[4];
#pragma unroll
    for (int nt = 0; nt < 4; ++nt) mv[nt] = mask[b * SEQ + kv0 + nt * 16 + lrow] * -1e9f;
#pragma unroll
    for (int mt = 0; mt < 2; ++mt)
#pragma unroll
      for (int nt = 0; nt < 4; ++nt)
#pragma unroll
        for (int r = 0; r < 4; ++r) s[mt][nt][r] = s[mt][nt][r] + mv[nt];

#pragma unroll
    for (int mt = 0; mt < 2; ++mt)
#pragma unroll
      for (int r = 0; r < 4; ++r) {
        float mx = fmaxf(fmaxf(s[mt][0][r], s[mt][1][r]), fmaxf(s[mt][2][r], s[mt][3][r]));
        mx = fmaxf(mx, __shfl_xor(mx, 1));
        mx = fmaxf(mx, __shfl_xor(mx, 2));
        mx = fmaxf(mx, __shfl_xor(mx, 4));
        mx = fmaxf(mx, __shfl_xor(mx, 8));
        float mnew = fmaxf(mreg[mt][r], mx);
        float corr = __expf(mreg[mt][r] - mnew);
        mreg[mt][r] = mnew;
        float p0 = __expf(s[mt][0][r] - mnew);
        float p1 = __expf(s[mt][1][r] - mnew);
        float p2 = __expf(s[mt][2][r] - mnew);
        float p3 = __expf(s[mt][3][r] - mnew);
        float rs = p0 + p1 + p2 + p3;
        rs += __shfl_xor(rs, 1);
        rs += __shfl_xor(rs, 2);
        rs += __shfl_xor(rs, 4);
        rs += __shfl_xor(rs, 8);
        lsum[mt][r] = lsum[mt][r] * corr + rs;
#pragma unroll
        for (int dn = 0; dn < 4; ++dn) oacc[mt][dn][r] = oacc[mt][dn][r] * corr;
        int prow = wave * 32 + mt * 16 + lgrp * 4 + r;
        Ps[prow * KPAD + 0 + lrow] = f2bf(p0);
        Ps[prow * KPAD + 16 + lrow] = f2bf(p1);
        Ps[prow * KPAD + 32 + lrow] = f2bf(p2);
        Ps[prow * KPAD + 48 + lrow] = f2bf(p3);
      }
    __syncthreads();
#pragma unroll
    for (int kk = 0; kk < 2; ++kk) {
      bf16x8 pf[2];
      pf[0] = *(const bf16x8*)(&Ps[(wave * 32 + 0 + lrow) * KPAD + kk * 32 + lgrp * 8]);
      pf[1] = *(const bf16x8*)(&Ps[(wave * 32 + 16 + lrow) * KPAD + kk * 32 + lgrp * 8]);
#pragma unroll
      for (int dn = 0; dn < 4; ++dn) {
        bf16x8 vf = *(const bf16x8*)(&Vs[(dn * 16 + lrow) * KPAD + kk * 32 + lgrp * 8]);
        oacc[0][dn] = __builtin_amdgcn_mfma_f32_16x16x32_bf16(pf[0], vf, oacc[0][dn], 0, 0, 0);
        oacc[1][dn] = __builtin_amdgcn_mfma_f32_16x16x32_bf16(pf[1], vf, oacc[1][dn], 0, 0, 0);
      }
    }
    __syncthreads();
  }
#pragma unroll
  for (int mt = 0; mt < 2; ++mt)
#pragma unroll
    for (int dn = 0; dn < 4; ++dn)
#pragma unroll
      for (int r = 0; r < 4; ++r) {
        int qrow = qrow0 + mt * 16 + lgrp * 4 + r;
        o[(size_t)(b * SEQ + qrow) * D_MODEL + hh * 64 + dn * 16 + lrow] =
            f2bf(oacc[mt][dn][r] / lsum[mt][r]);
      }
}

// ---------------- fused residual add + LayerNorm (f32 out + optional bf16 out) ----------------
__global__ __launch_bounds__(256) void ln_k(const float* __restrict__ a, const float* __restrict__ bres,
                                            const float* __restrict__ g, const float* __restrict__ be,
                                            float* __restrict__ out, u16* __restrict__ outb) {
  __shared__ float red[8];
  const int row = blockIdx.x, t = threadIdx.x;
  float4 va = *(const float4*)(a + (size_t)row * D_MODEL + t * 4);
  float4 vb = *(const float4*)(bres + (size_t)row * D_MODEL + t * 4);
  float x0 = va.x + vb.x, x1 = va.y + vb.y, x2 = va.z + vb.z, x3 = va.w + vb.w;
  float s = x0 + x1 + x2 + x3;
  float s2 = x0 * x0 + x1 * x1 + x2 * x2 + x3 * x3;
#pragma unroll
  for (int off = 1; off < 64; off <<= 1) {
    s += __shfl_xor(s, off);
    s2 += __shfl_xor(s2, off);
  }
  const int wave = t >> 6, lane = t & 63;
  if (lane == 0) { red[wave] = s; red[4 + wave] = s2; }
  __syncthreads();
  s = red[0] + red[1] + red[2] + red[3];
  s2 = red[4] + red[5] + red[6] + red[7];
  float mean = s * (1.f / D_MODEL);
  float var = s2 * (1.f / D_MODEL) - mean * mean;
  float inv = rsqrtf(var + 1e-6f);
  float4 vg = *(const float4*)(g + t * 4);
  float4 ve = *(const float4*)(be + t * 4);
  float4 r;
  r.x = (x0 - mean) * inv * vg.x + ve.x;
  r.y = (x1 - mean) * inv * vg.y + ve.y;
  r.z = (x2 - mean) * inv * vg.z + ve.z;
  r.w = (x3 - mean) * inv * vg.w + ve.w;
  *(float4*)(out + (size_t)row * D_MODEL + t * 4) = r;
  if (outb) {
    ushort4 w;
    w.x = f2bf(r.x); w.y = f2bf(r.y); w.z = f2bf(r.z); w.w = f2bf(r.w);
    *(ushort4*)(outb + (size_t)row * D_MODEL + t * 4) = w;
  }
}

// ---------------- launch ----------------
extern "C" void kernel_launch(void* const* d_in, const int* in_sizes, int n_in,
                              void* d_out, int out_size, void* d_ws, size_t ws_size,
                              hipStream_t stream) {
  const float* x = (const float*)d_in[0];
  const float* mask = (const float*)d_in[1];
  const float* Wq = (const float*)d_in[2];
  const float* bq = (const float*)d_in[3];
  const float* Wk = (const float*)d_in[4];
  const float* bk = (const float*)d_in[5];
  const float* Wv = (const float*)d_in[6];
  const float* bv = (const float*)d_in[7];
  const float* Wo = (const float*)d_in[8];
  const float* bo = (const float*)d_in[9];
  const float* W1 = (const float*)d_in[10];
  const float* b1 = (const float*)d_in[11];
  const float* W2 = (const float*)d_in[12];
  const float* b2 = (const float*)d_in[13];
  const float* g1 = (const float*)d_in[14];
  const float* be1 = (const float*)d_in[15];
  const float* g2 = (const float*)d_in[16];
  const float* be2 = (const float*)d_in[17];
  float* out = (float*)d_out;

  const size_t NTOK = (size_t)BATCH * SEQ;  // 2048
  const size_t ACT = NTOK * D_MODEL;        // 2M
  char* w = (char*)d_ws;
  float* h = (float*)w;    w += ACT * 4;
  float* h1 = (float*)w;   w += ACT * 4;
  float* op = (float*)w;   w += ACT * 4;            // o-proj / ffn2 f32 out
  u16* hb = (u16*)w;       w += ACT * 2;
  u16* h1b = (u16*)w;      w += ACT * 2;
  u16* qkvb = (u16*)w;     w += NTOK * 3072 * 2;    // fused q|k|v bf16
  u16* vt_ = (u16*)w;      w += ACT * 2;
  u16* obb = (u16*)w;      w += ACT * 2;            // attn out bf16
  u16* tb = (u16*)w;       w += NTOK * FF * 2;      // ffn1 out bf16
  u16* wqkv_t = (u16*)w;   w += (size_t)3072 * 1024 * 2;
  u16* wo_t = (u16*)w;     w += (size_t)1024 * 1024 * 2;
  u16* w1_t = (u16*)w;     w += (size_t)4096 * 1024 * 2;
  u16* w2_t = (u16*)w;     w += (size_t)1024 * 4096 * 2;
  float* bqkvb = (float*)w; w += 3072 * 4;

  posenc_k<<<(int)NTOK, 256, 0, stream>>>(x, h, hb);

  for (int l = 0; l < NLAYER; ++l) {
    const float* wq = Wq + (size_t)l * D_MODEL * D_MODEL;
    const float* wk = Wk + (size_t)l * D_MODEL * D_MODEL;
    const float* wv = Wv + (size_t)l * D_MODEL * D_MODEL;
    const float* wo = Wo + (size_t)l * D_MODEL * D_MODEL;
    const float* w1 = W1 + (size_t)l * D_MODEL * FF;
    const float* w2 = W2 + (size_t)l * FF * D_MODEL;
    const float* bql = bq + (size_t)l * D_MODEL;
    const float* bkl = bk + (size_t)l * D_MODEL;
    const float* bvl = bv + (size_t)l * D_MODEL;
    const float* bol = bo + (size_t)l * D_MODEL;
    const float* b1l = b1 + (size_t)l * FF;
    const float* b2l = b2 + (size_t)l * D_MODEL;
    const float* g1l = g1 + (size_t)l * D_MODEL;
    const float* be1l = be1 + (size_t)l * D_MODEL;
    const float* g2l = g2 + (size_t)l * D_MODEL;
    const float* be2l = be2 + (size_t)l * D_MODEL;

    // weight prep: transpose+convert to bf16 [N][K]; q-scale folded into Wq/bq
    wconv_k<<<dim3(32, 32), 256, 0, stream>>>(wq, wqkv_t, 1024, 1024, 0.125f);
    wconv_k<<<dim3(32, 32), 256, 0, stream>>>(wk, wqkv_t + (size_t)1024 * 1024, 1024, 1024, 1.f);
    wconv_k<<<dim3(32, 32), 256, 0, stream>>>(wv, wqkv_t + (size_t)2048 * 1024, 1024, 1024, 1.f);
    wconv_k<<<dim3(32, 32), 256, 0, stream>>>(wo, wo_t, 1024, 1024, 1.f);
    wconv_k<<<dim3(128, 32), 256, 0, stream>>>(w1, w1_t, 1024, 4096, 1.f);
    wconv_k<<<dim3(32, 128), 256, 0, stream>>>(w2, w2_t, 4096, 1024, 1.f);
    bqkv_k<<<12, 256, 0, stream>>>(bql, bkl, bvl, bqkvb);

    // fused QKV: [2048,3072] = hb @ wqkv_t^T
    gemm_bt<128, 1, 0><<<dim3(24, 16), 256, 0, stream>>>(hb, wqkv_t, bqkvb, qkvb, 3072, 1024);
    vtrans_k<<<dim3(16, 32, 4), 256, 0, stream>>>(qkvb, vt_);
    attn_k<<<dim3(4, 64), 256, 0, stream>>>(qkvb, vt_, mask, obb);
    gemm_bt<64, 0, 0><<<dim3(16, 16), 256, 0, stream>>>(obb, wo_t, bol, op, 1024, 1024);
    ln_k<<<(int)NTOK, 256, 0, stream>>>(h, op, g1l, be1l, h1, h1b);
    gemm_bt<128, 1, 1><<<dim3(32, 16), 256, 0, stream>>>(h1b, w1_t, b1l, tb, 4096, 1024);
    gemm_bt<64, 0, 0><<<dim3(16, 16), 256, 0, stream>>>(tb, w2_t, b2l, op, 1024, 4096);
    ln_k<<<(int)NTOK, 256, 0, stream>>>(h1, op, g2l, be2l, (l == NLAYER - 1) ? out : h, hb);
  }
}

// Round 4
// 1207.173 us; speedup vs baseline: 1.7356x; 1.1073x over previous
//
#include <hip/hip_runtime.h>

typedef __attribute__((ext_vector_type(8))) short bf16x8;
typedef __attribute__((ext_vector_type(4))) float f32x4;
typedef unsigned short u16;

#define D_MODEL 1024
#define SEQ 512
#define BATCH 4
#define NH 16
#define FF 4096
#define NLAYER 6

__device__ __forceinline__ u16 f2bf(float f) {
  unsigned int u = __float_as_uint(f);
  u += 0x7fffu + ((u >> 16) & 1u);
  return (u16)(u >> 16);
}

__device__ __forceinline__ void gload16(const void* g, void* lds) {
  __builtin_amdgcn_global_load_lds((const __attribute__((address_space(1))) void*)g,
                                   (__attribute__((address_space(3))) void*)lds, 16, 0, 0);
}

// ---------------- positional encoding: h = x + pe (f32 + bf16 outputs) ----------------
__global__ __launch_bounds__(256) void posenc_k(const float* __restrict__ x, float* __restrict__ h,
                                                u16* __restrict__ hb) {
  int row = blockIdx.x;  // b*512 + s
  int s = row & (SEQ - 1);
  int t = threadIdx.x;
  float4 v = *(const float4*)(x + (size_t)row * D_MODEL + t * 4);
  float r[4] = {v.x, v.y, v.z, v.w};
#pragma unroll
  for (int j = 0; j < 4; ++j) {
    int d = t * 4 + j;
    int p = d >> 1;
    float ang = (float)s * exp2f((float)p * (-2.0f / 1024.0f) * 13.287712379549449f);
    r[j] += (d & 1) ? cosf(ang) : sinf(ang);
  }
  float4 o = {r[0], r[1], r[2], r[3]};
  *(float4*)(h + (size_t)row * D_MODEL + t * 4) = o;
  ushort4 ob;
  ob.x = f2bf(r[0]); ob.y = f2bf(r[1]); ob.z = f2bf(r[2]); ob.w = f2bf(r[3]);
  *(ushort4*)(hb + (size_t)row * D_MODEL + t * 4) = ob;
}

// ---------------- weight transpose+convert: W[K][N] f32 -> Wt[N][K] bf16 (scaled) ----------------
#define TP 40
__global__ __launch_bounds__(256) void wconv_k(const float* __restrict__ W, u16* __restrict__ Wt,
                                               int K, int N, float scale) {
  __shared__ u16 tile[32 * TP];
  const int t = threadIdx.x;
  const int kb = blockIdx.y * 32, nb = blockIdx.x * 32;
#pragma unroll
  for (int j = 0; j < 4; ++j) {
    int idx = t + j * 256;
    int k = idx >> 5, n = idx & 31;
    tile[n * TP + k] = f2bf(W[(size_t)(kb + k) * N + nb + n] * scale);
  }
  __syncthreads();
  if (t < 128) {
    int n = t >> 2, kv = t & 3;
    uint4 v = *(const uint4*)&tile[n * TP + kv * 8];
    *(uint4*)&Wt[(size_t)(nb + n) * K + kb + kv * 8] = v;
  }
}

// qkv bias concat (scale folded for q)
__global__ __launch_bounds__(256) void bqkv_k(const float* bq, const float* bk, const float* bv,
                                              float* bqkv) {
  int i = blockIdx.x * 256 + threadIdx.x;
  float v = (i < 1024) ? bq[i] * 0.125f : (i < 2048 ? bk[i - 1024] : bv[i - 2048]);
  bqkv[i] = v;
}

// ---------------- GEMM: C = act(A@Bt^T + bias), 2-phase double-buffered ----------------
// A [M][K] bf16, Bt [N][K] bf16. 4 waves (2x2); global_load_lds dwordx4 staging.
// Per iter: barrier (tile t ready) -> issue stage(t+1 -> buf^1) -> ds_read+MFMA(buf).
template <int BM, int BN, int OBF, int RELU>
__global__ __launch_bounds__(256) void gemm_bt(const u16* __restrict__ A, const u16* __restrict__ Bt,
                                               const float* __restrict__ bias, void* __restrict__ Cv,
                                               int N, int K) {
  constexpr int WM = BM / 2, WN = BN / 2;
  constexpr int MR = WM / 16, NR = WN / 16;
  constexpr int ARND = (BM * 32) / 2048;  // 1KB wave-rounds for A tile
  constexpr int BRND = (BN * 32) / 2048;
  __shared__ u16 As[2][BM * 32];
  __shared__ u16 Bs[2][BN * 32];
  const int t = threadIdx.x, lane = t & 63, wave = t >> 6;
  const int wm = wave >> 1, wn = wave & 1;
  const int lrow = lane & 15, lgrp = lane >> 4;
  const int m0 = blockIdx.y * BM, n0 = blockIdx.x * BN;

  f32x4 acc[MR][NR];
#pragma unroll
  for (int i = 0; i < MR; ++i)
#pragma unroll
    for (int j = 0; j < NR; ++j) acc[i][j] = (f32x4){0.f, 0.f, 0.f, 0.f};

  const u16* Ag = A + (size_t)m0 * K;
  const u16* Bg = Bt + (size_t)n0 * K;

  auto stage = [&](int buf, int k0) {
#pragma unroll
    for (int r = 0; r < ARND; ++r) {
      int ebase = (wave * ARND + r) * 512;
      int e = ebase + lane * 8;
      int row = e >> 5, kc = e & 31;
      gload16(Ag + (size_t)row * K + k0 + kc, &As[buf][ebase]);
    }
#pragma unroll
    for (int r = 0; r < BRND; ++r) {
      int ebase = (wave * BRND + r) * 512;
      int e = ebase + lane * 8;
      int row = e >> 5, kc = e & 31;
      gload16(Bg + (size_t)row * K + k0 + kc, &Bs[buf][ebase]);
    }
  };

  stage(0, 0);
  const int nk = K / 32;
  for (int tt = 0; tt < nk; ++tt) {
    __syncthreads();  // drains vmcnt -> tile tt staged; prev compute done
    if (tt + 1 < nk) stage((tt + 1) & 1, (tt + 1) * 32);
    const int cur = tt & 1;
    bf16x8 af[MR], bfr[NR];
#pragma unroll
    for (int i = 0; i < MR; ++i)
      af[i] = *(const bf16x8*)&As[cur][(wm * WM + i * 16 + lrow) * 32 + lgrp * 8];
#pragma unroll
    for (int j = 0; j < NR; ++j)
      bfr[j] = *(const bf16x8*)&Bs[cur][(wn * WN + j * 16 + lrow) * 32 + lgrp * 8];
#pragma unroll
    for (int i = 0; i < MR; ++i)
#pragma unroll
      for (int j = 0; j < NR; ++j)
        acc[i][j] = __builtin_amdgcn_mfma_f32_16x16x32_bf16(af[i], bfr[j], acc[i][j], 0, 0, 0);
  }

#pragma unroll
  for (int j = 0; j < NR; ++j) {
    int col = n0 + wn * WN + j * 16 + lrow;
    float bv = bias[col];
#pragma unroll
    for (int i = 0; i < MR; ++i) {
      int rowb = m0 + wm * WM + i * 16 + lgrp * 4;
#pragma unroll
      for (int r = 0; r < 4; ++r) {
        float v = acc[i][j][r] + bv;
        if (RELU) v = fmaxf(v, 0.f);
        if (OBF)
          ((u16*)Cv)[(size_t)(rowb + r) * N + col] = f2bf(v);
        else
          ((float*)Cv)[(size_t)(rowb + r) * N + col] = v;
      }
    }
  }
}

// ---------------- V transpose from fused qkv: vt[(b*16+h)*64+d][s] ----------------
__global__ __launch_bounds__(256) void vtrans_k(const u16* __restrict__ qkv, u16* __restrict__ vt) {
  __shared__ u16 tile[32][33];
  const int bx = blockIdx.x, by = blockIdx.y, b = blockIdx.z;
  const int tx = threadIdx.x & 31, ty = threadIdx.x >> 5;
#pragma unroll
  for (int i = 0; i < 32; i += 8) {
    int sidx = bx * 32 + ty + i, d = by * 32 + tx;
    tile[ty + i][tx] = qkv[(size_t)(b * SEQ + sidx) * 3072 + 2048 + d];
  }
  __syncthreads();
#pragma unroll
  for (int i = 0; i < 32; i += 8) {
    int d = by * 32 + ty + i, sidx = bx * 32 + tx;
    vt[(size_t)(b * D_MODEL + d) * SEQ + sidx] = tile[tx][ty + i];
  }
}

// ---------------- fused flash attention (reads fused qkv, writes bf16) ----------------
#define KPAD 72
__global__ __launch_bounds__(256) void attn_k(const u16* __restrict__ qkv, const u16* __restrict__ vt,
                                              const float* __restrict__ mask, u16* __restrict__ o) {
  __shared__ u16 Ks[64 * KPAD];
  __shared__ u16 Vs[64 * KPAD];
  __shared__ u16 Ps[128 * KPAD];
  const int t = threadIdx.x;
  const int lane = t & 63, wave = t >> 6;
  const int lrow = lane & 15, lgrp = lane >> 4;
  const int qb = blockIdx.x;
  const int bh = blockIdx.y;
  const int b = bh >> 4, hh = bh & 15;

  bf16x8 qf[2][2];
  const int qrow0 = qb * 128 + wave * 32;
#pragma unroll
  for (int mt = 0; mt < 2; ++mt)
#pragma unroll
    for (int kk = 0; kk < 2; ++kk)
      qf[mt][kk] = *(const bf16x8*)(qkv + (size_t)(b * SEQ + qrow0 + mt * 16 + lrow) * 3072 +
                                    hh * 64 + kk * 32 + lgrp * 8);

  float mreg[2][4], lsum[2][4];
  f32x4 oacc[2][4];
#pragma unroll
  for (int mt = 0; mt < 2; ++mt)
#pragma unroll
    for (int r = 0; r < 4; ++r) { mreg[mt][r] = -1e30f; lsum[mt][r] = 0.f; }
#pragma unroll
  for (int mt = 0; mt < 2; ++mt)
#pragma unroll
    for (int dn = 0; dn < 4; ++dn) oacc[mt][dn] = (f32x4){0.f, 0.f, 0.f, 0.f};

  const int sr = t >> 3, sc = t & 7;
  for (int it = 0; it < 8; ++it) {
    const int kv0 = it * 64;
#pragma unroll
    for (int half = 0; half < 2; ++half) {
      int r = sr + half * 32;
      uint4 kv4 = *(const uint4*)(qkv + (size_t)(b * SEQ + kv0 + r) * 3072 + 1024 + hh * 64 + sc * 8);
      *(uint4*)(&Ks[r * KPAD + sc * 8]) = kv4;
      uint4 vv4 = *(const uint4*)(vt + (size_t)(bh * 64 + r) * SEQ + kv0 + sc * 8);
      *(uint4*)(&Vs[r * KPAD + sc * 8]) = vv4;
    }
    __syncthreads();

    f32x4 s[2][4];
#pragma unroll
    for (int mt = 0; mt < 2; ++mt)
#pragma unroll
      for (int nt = 0; nt < 4; ++nt) s[mt][nt] = (f32x4){0.f, 0.f, 0.f, 0.f};
#pragma unroll
    for (int nt = 0; nt < 4; ++nt)
#pragma unroll
      for (int kk = 0; kk < 2; ++kk) {
        bf16x8 kf = *(const bf16x8*)(&Ks[(nt * 16 + lrow) * KPAD + kk * 32 + lgrp * 8]);
#pragma unroll
        for (int mt = 0; mt < 2; ++mt)
          s[mt][nt] = __builtin_amdgcn_mfma_f32_16x16x32_bf16(qf[mt][kk], kf, s[mt][nt], 0, 0, 0);
      }
    float mv[4];
#pragma unroll
    for (int nt = 0; nt < 4; ++nt) mv[nt] = mask[b * SEQ + kv0 + nt * 16 + lrow] * -1e9f;
#pragma unroll
    for (int mt = 0; mt < 2; ++mt)
#pragma unroll
      for (int nt = 0; nt < 4; ++nt)
#pragma unroll
        for (int r = 0; r < 4; ++r) s[mt][nt][r] = s[mt][nt][r] + mv[nt];

#pragma unroll
    for (int mt = 0; mt < 2; ++mt)
#pragma unroll
      for (int r = 0; r < 4; ++r) {
        float mx = fmaxf(fmaxf(s[mt][0][r], s[mt][1][r]), fmaxf(s[mt][2][r], s[mt][3][r]));
        mx = fmaxf(mx, __shfl_xor(mx, 1));
        mx = fmaxf(mx, __shfl_xor(mx, 2));
        mx = fmaxf(mx, __shfl_xor(mx, 4));
        mx = fmaxf(mx, __shfl_xor(mx, 8));
        float mnew = fmaxf(mreg[mt][r], mx);
        float corr = __expf(mreg[mt][r] - mnew);
        mreg[mt][r] = mnew;
        float p0 = __expf(s[mt][0][r] - mnew);
        float p1 = __expf(s[mt][1][r] - mnew);
        float p2 = __expf(s[mt][2][r] - mnew);
        float p3 = __expf(s[mt][3][r] - mnew);
        float rs = p0 + p1 + p2 + p3;
        rs += __shfl_xor(rs, 1);
        rs += __shfl_xor(rs, 2);
        rs += __shfl_xor(rs, 4);
        rs += __shfl_xor(rs, 8);
        lsum[mt][r] = lsum[mt][r] * corr + rs;
#pragma unroll
        for (int dn = 0; dn < 4; ++dn) oacc[mt][dn][r] = oacc[mt][dn][r] * corr;
        int prow = wave * 32 + mt * 16 + lgrp * 4 + r;
        Ps[prow * KPAD + 0 + lrow] = f2bf(p0);
        Ps[prow * KPAD + 16 + lrow] = f2bf(p1);
        Ps[prow * KPAD + 32 + lrow] = f2bf(p2);
        Ps[prow * KPAD + 48 + lrow] = f2bf(p3);
      }
    __syncthreads();
#pragma unroll
    for (int kk = 0; kk < 2; ++kk) {
      bf16x8 pf[2];
      pf[0] = *(const bf16x8*)(&Ps[(wave * 32 + 0 + lrow) * KPAD + kk * 32 + lgrp * 8]);
      pf[1] = *(const bf16x8*)(&Ps[(wave * 32 + 16 + lrow) * KPAD + kk * 32 + lgrp * 8]);
#pragma unroll
      for (int dn = 0; dn < 4; ++dn) {
        bf16x8 vf = *(const bf16x8*)(&Vs[(dn * 16 + lrow) * KPAD + kk * 32 + lgrp * 8]);
        oacc[0][dn] = __builtin_amdgcn_mfma_f32_16x16x32_bf16(pf[0], vf, oacc[0][dn], 0, 0, 0);
        oacc[1][dn] = __builtin_amdgcn_mfma_f32_16x16x32_bf16(pf[1], vf, oacc[1][dn], 0, 0, 0);
      }
    }
    __syncthreads();
  }
#pragma unroll
  for (int mt = 0; mt < 2; ++mt)
#pragma unroll
    for (int dn = 0; dn < 4; ++dn)
#pragma unroll
      for (int r = 0; r < 4; ++r) {
        int qrow = qrow0 + mt * 16 + lgrp * 4 + r;
        o[(size_t)(b * SEQ + qrow) * D_MODEL + hh * 64 + dn * 16 + lrow] =
            f2bf(oacc[mt][dn][r] / lsum[mt][r]);
      }
}

// ---------------- fused residual add + LayerNorm (f32 out + optional bf16 out) ----------------
__global__ __launch_bounds__(256) void ln_k(const float* __restrict__ a, const float* __restrict__ bres,
                                            const float* __restrict__ g, const float* __restrict__ be,
                                            float* __restrict__ out, u16* __restrict__ outb) {
  __shared__ float red[8];
  const int row = blockIdx.x, t = threadIdx.x;
  float4 va = *(const float4*)(a + (size_t)row * D_MODEL + t * 4);
  float4 vb = *(const float4*)(bres + (size_t)row * D_MODEL + t * 4);
  float x0 = va.x + vb.x, x1 = va.y + vb.y, x2 = va.z + vb.z, x3 = va.w + vb.w;
  float s = x0 + x1 + x2 + x3;
  float s2 = x0 * x0 + x1 * x1 + x2 * x2 + x3 * x3;
#pragma unroll
  for (int off = 1; off < 64; off <<= 1) {
    s += __shfl_xor(s, off);
    s2 += __shfl_xor(s2, off);
  }
  const int wave = t >> 6, lane = t & 63;
  if (lane == 0) { red[wave] = s; red[4 + wave] = s2; }
  __syncthreads();
  s = red[0] + red[1] + red[2] + red[3];
  s2 = red[4] + red[5] + red[6] + red[7];
  float mean = s * (1.f / D_MODEL);
  float var = s2 * (1.f / D_MODEL) - mean * mean;
  float inv = rsqrtf(var + 1e-6f);
  float4 vg = *(const float4*)(g + t * 4);
  float4 ve = *(const float4*)(be + t * 4);
  float4 r;
  r.x = (x0 - mean) * inv * vg.x + ve.x;
  r.y = (x1 - mean) * inv * vg.y + ve.y;
  r.z = (x2 - mean) * inv * vg.z + ve.z;
  r.w = (x3 - mean) * inv * vg.w + ve.w;
  *(float4*)(out + (size_t)row * D_MODEL + t * 4) = r;
  if (outb) {
    ushort4 w;
    w.x = f2bf(r.x); w.y = f2bf(r.y); w.z = f2bf(r.z); w.w = f2bf(r.w);
    *(ushort4*)(outb + (size_t)row * D_MODEL + t * 4) = w;
  }
}

// ---------------- launch ----------------
extern "C" void kernel_launch(void* const* d_in, const int* in_sizes, int n_in,
                              void* d_out, int out_size, void* d_ws, size_t ws_size,
                              hipStream_t stream) {
  const float* x = (const float*)d_in[0];
  const float* mask = (const float*)d_in[1];
  const float* Wq = (const float*)d_in[2];
  const float* bq = (const float*)d_in[3];
  const float* Wk = (const float*)d_in[4];
  const float* bk = (const float*)d_in[5];
  const float* Wv = (const float*)d_in[6];
  const float* bv = (const float*)d_in[7];
  const float* Wo = (const float*)d_in[8];
  const float* bo = (const float*)d_in[9];
  const float* W1 = (const float*)d_in[10];
  const float* b1 = (const float*)d_in[11];
  const float* W2 = (const float*)d_in[12];
  const float* b2 = (const float*)d_in[13];
  const float* g1 = (const float*)d_in[14];
  const float* be1 = (const float*)d_in[15];
  const float* g2 = (const float*)d_in[16];
  const float* be2 = (const float*)d_in[17];
  float* out = (float*)d_out;

  const size_t NTOK = (size_t)BATCH * SEQ;  // 2048
  const size_t ACT = NTOK * D_MODEL;        // 2M
  char* w = (char*)d_ws;
  float* h = (float*)w;    w += ACT * 4;
  float* h1 = (float*)w;   w += ACT * 4;
  float* op = (float*)w;   w += ACT * 4;            // o-proj / ffn2 f32 out
  u16* hb = (u16*)w;       w += ACT * 2;
  u16* h1b = (u16*)w;      w += ACT * 2;
  u16* qkvb = (u16*)w;     w += NTOK * 3072 * 2;    // fused q|k|v bf16
  u16* vt_ = (u16*)w;      w += ACT * 2;
  u16* obb = (u16*)w;      w += ACT * 2;            // attn out bf16
  u16* tb = (u16*)w;       w += NTOK * FF * 2;      // ffn1 out bf16
  u16* wqkv_t = (u16*)w;   w += (size_t)3072 * 1024 * 2;
  u16* wo_t = (u16*)w;     w += (size_t)1024 * 1024 * 2;
  u16* w1_t = (u16*)w;     w += (size_t)4096 * 1024 * 2;
  u16* w2_t = (u16*)w;     w += (size_t)1024 * 4096 * 2;
  float* bqkvb = (float*)w; w += 3072 * 4;

  posenc_k<<<(int)NTOK, 256, 0, stream>>>(x, h, hb);

  for (int l = 0; l < NLAYER; ++l) {
    const float* wq = Wq + (size_t)l * D_MODEL * D_MODEL;
    const float* wk = Wk + (size_t)l * D_MODEL * D_MODEL;
    const float* wv = Wv + (size_t)l * D_MODEL * D_MODEL;
    const float* wo = Wo + (size_t)l * D_MODEL * D_MODEL;
    const float* w1 = W1 + (size_t)l * D_MODEL * FF;
    const float* w2 = W2 + (size_t)l * FF * D_MODEL;
    const float* bql = bq + (size_t)l * D_MODEL;
    const float* bkl = bk + (size_t)l * D_MODEL;
    const float* bvl = bv + (size_t)l * D_MODEL;
    const float* bol = bo + (size_t)l * D_MODEL;
    const float* b1l = b1 + (size_t)l * FF;
    const float* b2l = b2 + (size_t)l * D_MODEL;
    const float* g1l = g1 + (size_t)l * D_MODEL;
    const float* be1l = be1 + (size_t)l * D_MODEL;
    const float* g2l = g2 + (size_t)l * D_MODEL;
    const float* be2l = be2 + (size_t)l * D_MODEL;

    // weight prep: transpose+convert to bf16 [N][K]; q-scale folded into Wq/bq
    wconv_k<<<dim3(32, 32), 256, 0, stream>>>(wq, wqkv_t, 1024, 1024, 0.125f);
    wconv_k<<<dim3(32, 32), 256, 0, stream>>>(wk, wqkv_t + (size_t)1024 * 1024, 1024, 1024, 1.f);
    wconv_k<<<dim3(32, 32), 256, 0, stream>>>(wv, wqkv_t + (size_t)2048 * 1024, 1024, 1024, 1.f);
    wconv_k<<<dim3(32, 32), 256, 0, stream>>>(wo, wo_t, 1024, 1024, 1.f);
    wconv_k<<<dim3(128, 32), 256, 0, stream>>>(w1, w1_t, 1024, 4096, 1.f);
    wconv_k<<<dim3(32, 128), 256, 0, stream>>>(w2, w2_t, 4096, 1024, 1.f);
    bqkv_k<<<12, 256, 0, stream>>>(bql, bkl, bvl, bqkvb);

    // fused QKV: [2048,3072] = hb @ wqkv_t^T
    gemm_bt<128, 128, 1, 0><<<dim3(24, 16), 256, 0, stream>>>(hb, wqkv_t, bqkvb, qkvb, 3072, 1024);
    vtrans_k<<<dim3(16, 32, 4), 256, 0, stream>>>(qkvb, vt_);
    attn_k<<<dim3(4, 64), 256, 0, stream>>>(qkvb, vt_, mask, obb);
    gemm_bt<64, 64, 0, 0><<<dim3(16, 32), 256, 0, stream>>>(obb, wo_t, bol, op, 1024, 1024);
    ln_k<<<(int)NTOK, 256, 0, stream>>>(h, op, g1l, be1l, h1, h1b);
    gemm_bt<128, 128, 1, 1><<<dim3(32, 16), 256, 0, stream>>>(h1b, w1_t, b1l, tb, 4096, 1024);
    gemm_bt<64, 64, 0, 0><<<dim3(16, 32), 256, 0, stream>>>(tb, w2_t, b2l, op, 1024, 4096);
    ln_k<<<(int)NTOK, 256, 0, stream>>>(h1, op, g2l, be2l, (l == NLAYER - 1) ? out : h, hb);
  }
}

// Round 5
// 1197.429 us; speedup vs baseline: 1.7498x; 1.0081x over previous
//
#include <hip/hip_runtime.h>

typedef __attribute__((ext_vector_type(8))) short bf16x8;
typedef __attribute__((ext_vector_type(4))) float f32x4;
typedef unsigned short u16;

#define D_MODEL 1024
#define SEQ 512
#define BATCH 4
#define NH 16
#define FF 4096
#define NLAYER 6

__device__ __forceinline__ u16 f2bf(float f) {
  unsigned int u = __float_as_uint(f);
  u += 0x7fffu + ((u >> 16) & 1u);
  return (u16)(u >> 16);
}

__device__ __forceinline__ void gload16(const void* g, void* lds) {
  __builtin_amdgcn_global_load_lds((const __attribute__((address_space(1))) void*)g,
                                   (__attribute__((address_space(3))) void*)lds, 16, 0, 0);
}

// ---------------- positional encoding: h = x + pe (f32 + bf16 outputs) ----------------
__global__ __launch_bounds__(256) void posenc_k(const float* __restrict__ x, float* __restrict__ h,
                                                u16* __restrict__ hb) {
  int row = blockIdx.x;  // b*512 + s
  int s = row & (SEQ - 1);
  int t = threadIdx.x;
  float4 v = *(const float4*)(x + (size_t)row * D_MODEL + t * 4);
  float r[4] = {v.x, v.y, v.z, v.w};
#pragma unroll
  for (int j = 0; j < 4; ++j) {
    int d = t * 4 + j;
    int p = d >> 1;
    float ang = (float)s * exp2f((float)p * (-2.0f / 1024.0f) * 13.287712379549449f);
    r[j] += (d & 1) ? cosf(ang) : sinf(ang);
  }
  float4 o = {r[0], r[1], r[2], r[3]};
  *(float4*)(h + (size_t)row * D_MODEL + t * 4) = o;
  ushort4 ob;
  ob.x = f2bf(r[0]); ob.y = f2bf(r[1]); ob.z = f2bf(r[2]); ob.w = f2bf(r[3]);
  *(ushort4*)(hb + (size_t)row * D_MODEL + t * 4) = ob;
}

// ---------------- weight transpose+convert, 64x64 tiles ----------------
#define WTP 72  // padded k-stride (u16): 144B rows, 16B aligned
__device__ __forceinline__ void wconv_body(const float* __restrict__ src, u16* __restrict__ dst,
                                           int K, int N, float scale, int nb, int kb) {
  __shared__ u16 tile[64 * WTP];
  const int t = threadIdx.x;
#pragma unroll
  for (int rr = 0; rr < 4; ++rr) {
    int k = (t >> 4) + rr * 16;
    int n4 = (t & 15) * 4;
    float4 v = *(const float4*)(src + (size_t)(kb + k) * N + nb + n4);
    tile[(n4 + 0) * WTP + k] = f2bf(v.x * scale);
    tile[(n4 + 1) * WTP + k] = f2bf(v.y * scale);
    tile[(n4 + 2) * WTP + k] = f2bf(v.z * scale);
    tile[(n4 + 3) * WTP + k] = f2bf(v.w * scale);
  }
  __syncthreads();
#pragma unroll
  for (int rr = 0; rr < 2; ++rr) {
    int n = (t >> 3) + rr * 32;
    int kq = (t & 7) * 8;
    uint4 v = *(const uint4*)&tile[n * WTP + kq];
    *(uint4*)&dst[(size_t)(nb + n) * K + kb + kq] = v;
  }
}

// z = l*3 + which (q,k,v); all 6 layers in one dispatch
__global__ __launch_bounds__(256) void wconv_qkv_k(const float* __restrict__ Wq,
                                                   const float* __restrict__ Wk,
                                                   const float* __restrict__ Wv,
                                                   u16* __restrict__ dst) {
  int z = blockIdx.z, l = z / 3, which = z % 3;
  const float* src = (which == 0 ? Wq : which == 1 ? Wk : Wv) + (size_t)l * 1024 * 1024;
  u16* d = dst + (size_t)l * 3072 * 1024 + (size_t)which * 1024 * 1024;
  float scale = (which == 0) ? 0.125f : 1.0f;
  wconv_body(src, d, 1024, 1024, scale, blockIdx.x * 64, blockIdx.y * 64);
}

// z = layer
__global__ __launch_bounds__(256) void wconv_gen_k(const float* __restrict__ W, u16* __restrict__ dst,
                                                   int K, int N) {
  int z = blockIdx.z;
  wconv_body(W + (size_t)z * K * N, dst + (size_t)z * N * K, K, N, 1.0f,
             blockIdx.x * 64, blockIdx.y * 64);
}

// all-layer qkv bias concat (q scaled)
__global__ __launch_bounds__(256) void bqkv_k(const float* bq, const float* bk, const float* bv,
                                              float* o) {
  int i = blockIdx.x * 256 + threadIdx.x;  // 18432
  int l = i / 3072, j = i % 3072;
  float v = (j < 1024) ? bq[l * 1024 + j] * 0.125f
                       : (j < 2048 ? bk[l * 1024 + j - 1024] : bv[l * 1024 + j - 2048]);
  o[i] = v;
}

// ---------------- GEMM: C = act(A@Bt^T + bias), 3-buffer counted-vmcnt pipeline ----------------
// A [M][K] bf16, Bt [N][K] bf16. 4 waves (2x2); global_load_lds dwordx4 staging.
template <int BM, int BN, int OBF, int RELU>
__global__ __launch_bounds__(256) void gemm_bt(const u16* __restrict__ A, const u16* __restrict__ Bt,
                                               const float* __restrict__ bias, void* __restrict__ Cv,
                                               int N, int K) {
  constexpr int WM = BM / 2, WN = BN / 2;
  constexpr int MR = WM / 16, NR = WN / 16;
  constexpr int ARND = (BM * 32) / 2048;  // 1KB wave-rounds for A tile
  constexpr int BRND = (BN * 32) / 2048;
  constexpr int LOADS = ARND + BRND;  // vmem instrs per tile per thread
  __shared__ u16 As[3][BM * 32];
  __shared__ u16 Bs[3][BN * 32];
  const int t = threadIdx.x, lane = t & 63, wave = t >> 6;
  const int wm = wave >> 1, wn = wave & 1;
  const int lrow = lane & 15, lgrp = lane >> 4;
  const int m0 = blockIdx.y * BM, n0 = blockIdx.x * BN;

  f32x4 acc[MR][NR];
#pragma unroll
  for (int i = 0; i < MR; ++i)
#pragma unroll
    for (int j = 0; j < NR; ++j) acc[i][j] = (f32x4){0.f, 0.f, 0.f, 0.f};

  const u16* Ag = A + (size_t)m0 * K;
  const u16* Bg = Bt + (size_t)n0 * K;

  auto stage = [&](int buf, int k0) {
#pragma unroll
    for (int r = 0; r < ARND; ++r) {
      int ebase = (wave * ARND + r) * 512;
      int e = ebase + lane * 8;
      int row = e >> 5, kc = e & 31;
      gload16(Ag + (size_t)row * K + k0 + kc, &As[buf][ebase]);
    }
#pragma unroll
    for (int r = 0; r < BRND; ++r) {
      int ebase = (wave * BRND + r) * 512;
      int e = ebase + lane * 8;
      int row = e >> 5, kc = e & 31;
      gload16(Bg + (size_t)row * K + k0 + kc, &Bs[buf][ebase]);
    }
  };

  const int nk = K / 32;
  stage(0, 0);
  stage(1, 32);
  for (int tt = 0; tt < nk; ++tt) {
    // wait for tile tt's loads; keep tile tt+1's loads in flight (never drain mid-loop)
    if (tt + 1 < nk) {
      if constexpr (LOADS == 4) asm volatile("s_waitcnt vmcnt(4)" ::: "memory");
      else asm volatile("s_waitcnt vmcnt(2)" ::: "memory");
    } else {
      asm volatile("s_waitcnt vmcnt(0)" ::: "memory");
    }
    __builtin_amdgcn_s_barrier();
    __builtin_amdgcn_sched_barrier(0);
    if (tt + 2 < nk) stage((tt + 2) % 3, (tt + 2) * 32);
    const int cur = tt % 3;
    bf16x8 af[MR], bfr[NR];
#pragma unroll
    for (int i = 0; i < MR; ++i)
      af[i] = *(const bf16x8*)&As[cur][(wm * WM + i * 16 + lrow) * 32 + lgrp * 8];
#pragma unroll
    for (int j = 0; j < NR; ++j)
      bfr[j] = *(const bf16x8*)&Bs[cur][(wn * WN + j * 16 + lrow) * 32 + lgrp * 8];
#pragma unroll
    for (int i = 0; i < MR; ++i)
#pragma unroll
      for (int j = 0; j < NR; ++j)
        acc[i][j] = __builtin_amdgcn_mfma_f32_16x16x32_bf16(af[i], bfr[j], acc[i][j], 0, 0, 0);
  }

#pragma unroll
  for (int j = 0; j < NR; ++j) {
    int col = n0 + wn * WN + j * 16 + lrow;
    float bv = bias[col];
#pragma unroll
    for (int i = 0; i < MR; ++i) {
      int rowb = m0 + wm * WM + i * 16 + lgrp * 4;
#pragma unroll
      for (int r = 0; r < 4; ++r) {
        float v = acc[i][j][r] + bv;
        if (RELU) v = fmaxf(v, 0.f);
        if (OBF)
          ((u16*)Cv)[(size_t)(rowb + r) * N + col] = f2bf(v);
        else
          ((float*)Cv)[(size_t)(rowb + r) * N + col] = v;
      }
    }
  }
}

// ---------------- V transpose from fused qkv: vt[(b*16+h)*64+d][s] ----------------
__global__ __launch_bounds__(256) void vtrans_k(const u16* __restrict__ qkv, u16* __restrict__ vt) {
  __shared__ u16 tile[32][33];
  const int bx = blockIdx.x, by = blockIdx.y, b = blockIdx.z;
  const int tx = threadIdx.x & 31, ty = threadIdx.x >> 5;
#pragma unroll
  for (int i = 0; i < 32; i += 8) {
    int sidx = bx * 32 + ty + i, d = by * 32 + tx;
    tile[ty + i][tx] = qkv[(size_t)(b * SEQ + sidx) * 3072 + 2048 + d];
  }
  __syncthreads();
#pragma unroll
  for (int i = 0; i < 32; i += 8) {
    int d = by * 32 + ty + i, sidx = bx * 32 + tx;
    vt[(size_t)(b * D_MODEL + d) * SEQ + sidx] = tile[tx][ty + i];
  }
}

// ---------------- fused flash attention: 64 q-rows/block, 4 waves x 16 rows ----------------
#define KPAD 72
__global__ __launch_bounds__(256) void attn_k(const u16* __restrict__ qkv, const u16* __restrict__ vt,
                                              const float* __restrict__ mask, u16* __restrict__ o) {
  __shared__ u16 Ks[64 * KPAD];
  __shared__ u16 Vs[64 * KPAD];
  __shared__ u16 Ps[64 * KPAD];
  const int t = threadIdx.x;
  const int lane = t & 63, wave = t >> 6;
  const int lrow = lane & 15, lgrp = lane >> 4;
  const int qb = blockIdx.x;
  const int bh = blockIdx.y;
  const int b = bh >> 4, hh = bh & 15;

  bf16x8 qf[2];
  const int qrow0 = qb * 64 + wave * 16;
#pragma unroll
  for (int kk = 0; kk < 2; ++kk)
    qf[kk] = *(const bf16x8*)(qkv + (size_t)(b * SEQ + qrow0 + lrow) * 3072 +
                              hh * 64 + kk * 32 + lgrp * 8);

  float mreg[4], lsum[4];
  f32x4 oacc[4];
#pragma unroll
  for (int r = 0; r < 4; ++r) { mreg[r] = -1e30f; lsum[r] = 0.f; }
#pragma unroll
  for (int dn = 0; dn < 4; ++dn) oacc[dn] = (f32x4){0.f, 0.f, 0.f, 0.f};

  const int sr = t >> 3, sc = t & 7;
  for (int it = 0; it < 8; ++it) {
    const int kv0 = it * 64;
#pragma unroll
    for (int half = 0; half < 2; ++half) {
      int r = sr + half * 32;
      uint4 kv4 = *(const uint4*)(qkv + (size_t)(b * SEQ + kv0 + r) * 3072 + 1024 + hh * 64 + sc * 8);
      *(uint4*)(&Ks[r * KPAD + sc * 8]) = kv4;
      uint4 vv4 = *(const uint4*)(vt + (size_t)(bh * 64 + r) * SEQ + kv0 + sc * 8);
      *(uint4*)(&Vs[r * KPAD + sc * 8]) = vv4;
    }
    __syncthreads();

    f32x4 s[4];
#pragma unroll
    for (int nt = 0; nt < 4; ++nt) s[nt] = (f32x4){0.f, 0.f, 0.f, 0.f};
#pragma unroll
    for (int nt = 0; nt < 4; ++nt)
#pragma unroll
      for (int kk = 0; kk < 2; ++kk) {
        bf16x8 kf = *(const bf16x8*)(&Ks[(nt * 16 + lrow) * KPAD + kk * 32 + lgrp * 8]);
        s[nt] = __builtin_amdgcn_mfma_f32_16x16x32_bf16(qf[kk], kf, s[nt], 0, 0, 0);
      }
    float mv[4];
#pragma unroll
    for (int nt = 0; nt < 4; ++nt) mv[nt] = mask[b * SEQ + kv0 + nt * 16 + lrow] * -1e9f;
#pragma unroll
    for (int nt = 0; nt < 4; ++nt)
#pragma unroll
      for (int r = 0; r < 4; ++r) s[nt][r] = s[nt][r] + mv[nt];

#pragma unroll
    for (int r = 0; r < 4; ++r) {
      float mx = fmaxf(fmaxf(s[0][r], s[1][r]), fmaxf(s[2][r], s[3][r]));
      mx = fmaxf(mx, __shfl_xor(mx, 1));
      mx = fmaxf(mx, __shfl_xor(mx, 2));
      mx = fmaxf(mx, __shfl_xor(mx, 4));
      mx = fmaxf(mx, __shfl_xor(mx, 8));
      float mnew = fmaxf(mreg[r], mx);
      float corr = __expf(mreg[r] - mnew);
      mreg[r] = mnew;
      float p0 = __expf(s[0][r] - mnew);
      float p1 = __expf(s[1][r] - mnew);
      float p2 = __expf(s[2][r] - mnew);
      float p3 = __expf(s[3][r] - mnew);
      float rs = p0 + p1 + p2 + p3;
      rs += __shfl_xor(rs, 1);
      rs += __shfl_xor(rs, 2);
      rs += __shfl_xor(rs, 4);
      rs += __shfl_xor(rs, 8);
      lsum[r] = lsum[r] * corr + rs;
#pragma unroll
      for (int dn = 0; dn < 4; ++dn) oacc[dn][r] = oacc[dn][r] * corr;
      int prow = wave * 16 + lgrp * 4 + r;
      Ps[prow * KPAD + 0 + lrow] = f2bf(p0);
      Ps[prow * KPAD + 16 + lrow] = f2bf(p1);
      Ps[prow * KPAD + 32 + lrow] = f2bf(p2);
      Ps[prow * KPAD + 48 + lrow] = f2bf(p3);
    }
    __syncthreads();
#pragma unroll
    for (int kk = 0; kk < 2; ++kk) {
      bf16x8 pf = *(const bf16x8*)(&Ps[(wave * 16 + lrow) * KPAD + kk * 32 + lgrp * 8]);
#pragma unroll
      for (int dn = 0; dn < 4; ++dn) {
        bf16x8 vf = *(const bf16x8*)(&Vs[(dn * 16 + lrow) * KPAD + kk * 32 + lgrp * 8]);
        oacc[dn] = __builtin_amdgcn_mfma_f32_16x16x32_bf16(pf, vf, oacc[dn], 0, 0, 0);
      }
    }
    __syncthreads();
  }
#pragma unroll
  for (int dn = 0; dn < 4; ++dn)
#pragma unroll
    for (int r = 0; r < 4; ++r) {
      int qrow = qrow0 + lgrp * 4 + r;
      o[(size_t)(b * SEQ + qrow) * D_MODEL + hh * 64 + dn * 16 + lrow] =
          f2bf(oacc[dn][r] / lsum[r]);
    }
}

// ---------------- fused residual add + LayerNorm (f32 out + optional bf16 out) ----------------
__global__ __launch_bounds__(256) void ln_k(const float* __restrict__ a, const float* __restrict__ bres,
                                            const float* __restrict__ g, const float* __restrict__ be,
                                            float* __restrict__ out, u16* __restrict__ outb) {
  __shared__ float red[8];
  const int row = blockIdx.x, t = threadIdx.x;
  float4 va = *(const float4*)(a + (size_t)row * D_MODEL + t * 4);
  float4 vb = *(const float4*)(bres + (size_t)row * D_MODEL + t * 4);
  float x0 = va.x + vb.x, x1 = va.y + vb.y, x2 = va.z + vb.z, x3 = va.w + vb.w;
  float s = x0 + x1 + x2 + x3;
  float s2 = x0 * x0 + x1 * x1 + x2 * x2 + x3 * x3;
#pragma unroll
  for (int off = 1; off < 64; off <<= 1) {
    s += __shfl_xor(s, off);
    s2 += __shfl_xor(s2, off);
  }
  const int wave = t >> 6, lane = t & 63;
  if (lane == 0) { red[wave] = s; red[4 + wave] = s2; }
  __syncthreads();
  s = red[0] + red[1] + red[2] + red[3];
  s2 = red[4] + red[5] + red[6] + red[7];
  float mean = s * (1.f / D_MODEL);
  float var = s2 * (1.f / D_MODEL) - mean * mean;
  float inv = rsqrtf(var + 1e-6f);
  float4 vg = *(const float4*)(g + t * 4);
  float4 ve = *(const float4*)(be + t * 4);
  float4 r;
  r.x = (x0 - mean) * inv * vg.x + ve.x;
  r.y = (x1 - mean) * inv * vg.y + ve.y;
  r.z = (x2 - mean) * inv * vg.z + ve.z;
  r.w = (x3 - mean) * inv * vg.w + ve.w;
  *(float4*)(out + (size_t)row * D_MODEL + t * 4) = r;
  if (outb) {
    ushort4 w;
    w.x = f2bf(r.x); w.y = f2bf(r.y); w.z = f2bf(r.z); w.w = f2bf(r.w);
    *(ushort4*)(outb + (size_t)row * D_MODEL + t * 4) = w;
  }
}

// ---------------- launch ----------------
extern "C" void kernel_launch(void* const* d_in, const int* in_sizes, int n_in,
                              void* d_out, int out_size, void* d_ws, size_t ws_size,
                              hipStream_t stream) {
  const float* x = (const float*)d_in[0];
  const float* mask = (const float*)d_in[1];
  const float* Wq = (const float*)d_in[2];
  const float* bq = (const float*)d_in[3];
  const float* Wk = (const float*)d_in[4];
  const float* bk = (const float*)d_in[5];
  const float* Wv = (const float*)d_in[6];
  const float* bv = (const float*)d_in[7];
  const float* Wo = (const float*)d_in[8];
  const float* bo = (const float*)d_in[9];
  const float* W1 = (const float*)d_in[10];
  const float* b1 = (const float*)d_in[11];
  const float* W2 = (const float*)d_in[12];
  const float* b2 = (const float*)d_in[13];
  const float* g1 = (const float*)d_in[14];
  const float* be1 = (const float*)d_in[15];
  const float* g2 = (const float*)d_in[16];
  const float* be2 = (const float*)d_in[17];
  float* out = (float*)d_out;

  const size_t NTOK = (size_t)BATCH * SEQ;  // 2048
  const size_t ACT = NTOK * D_MODEL;        // 2M
  char* w = (char*)d_ws;
  float* h = (float*)w;     w += ACT * 4;
  float* h1 = (float*)w;    w += ACT * 4;
  float* op = (float*)w;    w += ACT * 4;           // o-proj / ffn2 f32 out
  u16* hb = (u16*)w;        w += ACT * 2;
  u16* h1b = (u16*)w;       w += ACT * 2;
  u16* qkvb = (u16*)w;      w += NTOK * 3072 * 2;   // fused q|k|v bf16
  u16* vt_ = (u16*)w;       w += ACT * 2;
  u16* obb = (u16*)w;       w += ACT * 2;           // attn out bf16
  u16* tb = (u16*)w;        w += NTOK * FF * 2;     // ffn1 out bf16
  u16* wqkv_all = (u16*)w;  w += (size_t)NLAYER * 3072 * 1024 * 2;
  u16* wo_all = (u16*)w;    w += (size_t)NLAYER * 1024 * 1024 * 2;
  u16* w1_all = (u16*)w;    w += (size_t)NLAYER * 4096 * 1024 * 2;
  u16* w2_all = (u16*)w;    w += (size_t)NLAYER * 1024 * 4096 * 2;
  float* bqkv_all = (float*)w; w += (size_t)NLAYER * 3072 * 4;

  // upfront: posenc + all-layer weight conversion (5 dispatches)
  posenc_k<<<(int)NTOK, 256, 0, stream>>>(x, h, hb);
  wconv_qkv_k<<<dim3(16, 16, 18), 256, 0, stream>>>(Wq, Wk, Wv, wqkv_all);
  wconv_gen_k<<<dim3(16, 16, 6), 256, 0, stream>>>(Wo, wo_all, 1024, 1024);
  wconv_gen_k<<<dim3(64, 16, 6), 256, 0, stream>>>(W1, w1_all, 1024, 4096);
  wconv_gen_k<<<dim3(16, 64, 6), 256, 0, stream>>>(W2, w2_all, 4096, 1024);
  bqkv_k<<<72, 256, 0, stream>>>(bq, bk, bv, bqkv_all);

  for (int l = 0; l < NLAYER; ++l) {
    const u16* wqkv_t = wqkv_all + (size_t)l * 3072 * 1024;
    const u16* wo_t = wo_all + (size_t)l * 1024 * 1024;
    const u16* w1_t = w1_all + (size_t)l * 4096 * 1024;
    const u16* w2_t = w2_all + (size_t)l * 1024 * 4096;
    const float* bqkvl = bqkv_all + (size_t)l * 3072;
    const float* bol = bo + (size_t)l * D_MODEL;
    const float* b1l = b1 + (size_t)l * FF;
    const float* b2l = b2 + (size_t)l * D_MODEL;
    const float* g1l = g1 + (size_t)l * D_MODEL;
    const float* be1l = be1 + (size_t)l * D_MODEL;
    const float* g2l = g2 + (size_t)l * D_MODEL;
    const float* be2l = be2 + (size_t)l * D_MODEL;

    gemm_bt<128, 128, 1, 0><<<dim3(24, 16), 256, 0, stream>>>(hb, wqkv_t, bqkvl, qkvb, 3072, 1024);
    vtrans_k<<<dim3(16, 32, 4), 256, 0, stream>>>(qkvb, vt_);
    attn_k<<<dim3(8, 64), 256, 0, stream>>>(qkvb, vt_, mask, obb);
    gemm_bt<64, 64, 0, 0><<<dim3(16, 32), 256, 0, stream>>>(obb, wo_t, bol, op, 1024, 1024);
    ln_k<<<(int)NTOK, 256, 0, stream>>>(h, op, g1l, be1l, h1, h1b);
    gemm_bt<128, 128, 1, 1><<<dim3(32, 16), 256, 0, stream>>>(h1b, w1_t, b1l, tb, 4096, 1024);
    gemm_bt<64, 64, 0, 0><<<dim3(16, 32), 256, 0, stream>>>(tb, w2_t, b2l, op, 1024, 4096);
    ln_k<<<(int)NTOK, 256, 0, stream>>>(h1, op, g2l, be2l, (l == NLAYER - 1) ? out : h, hb);
  }
}

// Round 6
// 1163.029 us; speedup vs baseline: 1.8015x; 1.0296x over previous
//
#include <hip/hip_runtime.h>

typedef __attribute__((ext_vector_type(8))) short bf16x8;
typedef __attribute__((ext_vector_type(4))) float f32x4;
typedef unsigned short u16;

#define D_MODEL 1024
#define SEQ 512
#define BATCH 4
#define NH 16
#define FF 4096
#define NLAYER 6
#define NTOKS 2048

__device__ __forceinline__ u16 f2bf(float f) {
  unsigned int u = __float_as_uint(f);
  u += 0x7fffu + ((u >> 16) & 1u);
  return (u16)(u >> 16);
}

__device__ __forceinline__ void gload16(const void* g, void* lds) {
  __builtin_amdgcn_global_load_lds((const __attribute__((address_space(1))) void*)g,
                                   (__attribute__((address_space(3))) void*)lds, 16, 0, 0);
}

// ---------------- positional encoding: h = x + pe (f32 + bf16 outputs) ----------------
__global__ __launch_bounds__(256) void posenc_k(const float* __restrict__ x, float* __restrict__ h,
                                                u16* __restrict__ hb) {
  int row = blockIdx.x;  // b*512 + s
  int s = row & (SEQ - 1);
  int t = threadIdx.x;
  float4 v = *(const float4*)(x + (size_t)row * D_MODEL + t * 4);
  float r[4] = {v.x, v.y, v.z, v.w};
#pragma unroll
  for (int j = 0; j < 4; ++j) {
    int d = t * 4 + j;
    int p = d >> 1;
    float ang = (float)s * exp2f((float)p * (-2.0f / 1024.0f) * 13.287712379549449f);
    r[j] += (d & 1) ? cosf(ang) : sinf(ang);
  }
  float4 o = {r[0], r[1], r[2], r[3]};
  *(float4*)(h + (size_t)row * D_MODEL + t * 4) = o;
  ushort4 ob;
  ob.x = f2bf(r[0]); ob.y = f2bf(r[1]); ob.z = f2bf(r[2]); ob.w = f2bf(r[3]);
  *(ushort4*)(hb + (size_t)row * D_MODEL + t * 4) = ob;
}

// ---------------- weight transpose+convert, 64x64 tiles ----------------
#define WTP 72  // padded k-stride (u16)
__device__ __forceinline__ void wconv_body(const float* __restrict__ src, u16* __restrict__ dst,
                                           int K, int N, float scale, int nb, int kb) {
  __shared__ u16 tile[64 * WTP];
  const int t = threadIdx.x;
#pragma unroll
  for (int rr = 0; rr < 4; ++rr) {
    int k = (t >> 4) + rr * 16;
    int n4 = (t & 15) * 4;
    float4 v = *(const float4*)(src + (size_t)(kb + k) * N + nb + n4);
    tile[(n4 + 0) * WTP + k] = f2bf(v.x * scale);
    tile[(n4 + 1) * WTP + k] = f2bf(v.y * scale);
    tile[(n4 + 2) * WTP + k] = f2bf(v.z * scale);
    tile[(n4 + 3) * WTP + k] = f2bf(v.w * scale);
  }
  __syncthreads();
#pragma unroll
  for (int rr = 0; rr < 2; ++rr) {
    int n = (t >> 3) + rr * 32;
    int kq = (t & 7) * 8;
    uint4 v = *(const uint4*)&tile[n * WTP + kq];
    *(uint4*)&dst[(size_t)(nb + n) * K + kb + kq] = v;
  }
}

__global__ __launch_bounds__(256) void wconv_qkv_k(const float* __restrict__ Wq,
                                                   const float* __restrict__ Wk,
                                                   const float* __restrict__ Wv,
                                                   u16* __restrict__ dst) {
  int z = blockIdx.z, l = z / 3, which = z % 3;
  const float* src = (which == 0 ? Wq : which == 1 ? Wk : Wv) + (size_t)l * 1024 * 1024;
  u16* d = dst + (size_t)l * 3072 * 1024 + (size_t)which * 1024 * 1024;
  float scale = (which == 0) ? 0.125f : 1.0f;
  wconv_body(src, d, 1024, 1024, scale, blockIdx.x * 64, blockIdx.y * 64);
}

__global__ __launch_bounds__(256) void wconv_gen_k(const float* __restrict__ W, u16* __restrict__ dst,
                                                   int K, int N) {
  int z = blockIdx.z;
  wconv_body(W + (size_t)z * K * N, dst + (size_t)z * N * K, K, N, 1.0f,
             blockIdx.x * 64, blockIdx.y * 64);
}

__global__ __launch_bounds__(256) void bqkv_k(const float* bq, const float* bk, const float* bv,
                                              float* o) {
  int i = blockIdx.x * 256 + threadIdx.x;  // 18432
  int l = i / 3072, j = i % 3072;
  float v = (j < 1024) ? bq[l * 1024 + j] * 0.125f
                       : (j < 2048 ? bk[l * 1024 + j - 1024] : bv[l * 1024 + j - 2048]);
  o[i] = v;
}

// ---------------- GEMM 64x64, 4 waves, 4-buffer depth-3 counted-vmcnt pipeline ----------------
// A [2048][K] bf16, Bt [N][K] bf16. KSPLIT>1: grid.z splits K; partials to Cv + z*2048*N (f32).
template <int OBF, int RELU, int KSPLIT>
__global__ __launch_bounds__(256) void gemm64_k(const u16* __restrict__ A, const u16* __restrict__ Bt,
                                                const float* __restrict__ bias, void* __restrict__ Cv,
                                                int N, int K) {
  __shared__ u16 As[4][64 * 32];
  __shared__ u16 Bs[4][64 * 32];
  const int t = threadIdx.x, lane = t & 63, wave = t >> 6;
  const int wm = wave >> 1, wn = wave & 1;
  const int lrow = lane & 15, lgrp = lane >> 4;
  const int m0 = blockIdx.y * 64, n0 = blockIdx.x * 64;
  const int kseg = K / KSPLIT;
  const int koff = (KSPLIT > 1) ? blockIdx.z * kseg : 0;

  f32x4 acc[2][2];
#pragma unroll
  for (int i = 0; i < 2; ++i)
#pragma unroll
    for (int j = 0; j < 2; ++j) acc[i][j] = (f32x4){0.f, 0.f, 0.f, 0.f};

  const u16* Ag = A + (size_t)m0 * K + koff;
  const u16* Bg = Bt + (size_t)n0 * K + koff;
  const int ebase = wave * 512;           // wave-uniform LDS dest (u16)
  const int e = ebase + lane * 8;
  const int srow = e >> 5, skc = e & 31;  // lane's global source element

  auto stage = [&](int buf, int k0) {
    gload16(Ag + (size_t)srow * K + k0 + skc, &As[buf][ebase]);
    gload16(Bg + (size_t)srow * K + k0 + skc, &Bs[buf][ebase]);
  };

  const int nk = kseg / 32;
  stage(0, 0);
  stage(1, 32);
  stage(2, 64);
  for (int tt = 0; tt < nk; ++tt) {
    // wait for tile tt only; keep tiles tt+1, tt+2 in flight (2 instrs each)
    if (tt + 2 < nk) asm volatile("s_waitcnt vmcnt(4)" ::: "memory");
    else if (tt + 1 < nk) asm volatile("s_waitcnt vmcnt(2)" ::: "memory");
    else asm volatile("s_waitcnt vmcnt(0)" ::: "memory");
    __builtin_amdgcn_s_barrier();
    __builtin_amdgcn_sched_barrier(0);
    if (tt + 3 < nk) stage((tt + 3) & 3, (tt + 3) * 32);
    const int cur = tt & 3;
    bf16x8 af[2], bfr[2];
#pragma unroll
    for (int i = 0; i < 2; ++i)
      af[i] = *(const bf16x8*)&As[cur][(wm * 32 + i * 16 + lrow) * 32 + lgrp * 8];
#pragma unroll
    for (int j = 0; j < 2; ++j)
      bfr[j] = *(const bf16x8*)&Bs[cur][(wn * 32 + j * 16 + lrow) * 32 + lgrp * 8];
#pragma unroll
    for (int i = 0; i < 2; ++i)
#pragma unroll
      for (int j = 0; j < 2; ++j)
        acc[i][j] = __builtin_amdgcn_mfma_f32_16x16x32_bf16(af[i], bfr[j], acc[i][j], 0, 0, 0);
  }

  const size_t outoff = (KSPLIT > 1) ? (size_t)blockIdx.z * NTOKS * N : 0;
#pragma unroll
  for (int j = 0; j < 2; ++j) {
    int col = n0 + wn * 32 + j * 16 + lrow;
    float bv = (KSPLIT == 1 || blockIdx.z == 0) ? bias[col] : 0.f;
#pragma unroll
    for (int i = 0; i < 2; ++i) {
      int rowb = m0 + wm * 32 + i * 16 + lgrp * 4;
#pragma unroll
      for (int r = 0; r < 4; ++r) {
        float v = acc[i][j][r] + bv;
        if (RELU) v = fmaxf(v, 0.f);
        if (OBF)
          ((u16*)Cv)[(size_t)(rowb + r) * N + col] = f2bf(v);
        else
          ((float*)Cv)[outoff + (size_t)(rowb + r) * N + col] = v;
      }
    }
  }
}

// ---------------- V transpose from fused qkv: vt[(b*16+h)*64+d][s] ----------------
__global__ __launch_bounds__(256) void vtrans_k(const u16* __restrict__ qkv, u16* __restrict__ vt) {
  __shared__ u16 tile[32][33];
  const int bx = blockIdx.x, by = blockIdx.y, b = blockIdx.z;
  const int tx = threadIdx.x & 31, ty = threadIdx.x >> 5;
#pragma unroll
  for (int i = 0; i < 32; i += 8) {
    int sidx = bx * 32 + ty + i, d = by * 32 + tx;
    tile[ty + i][tx] = qkv[(size_t)(b * SEQ + sidx) * 3072 + 2048 + d];
  }
  __syncthreads();
#pragma unroll
  for (int i = 0; i < 32; i += 8) {
    int d = by * 32 + ty + i, sidx = bx * 32 + tx;
    vt[(size_t)(b * D_MODEL + d) * SEQ + sidx] = tile[tx][ty + i];
  }
}

// ---------------- fused flash attention: 64 q-rows/block, 4 waves x 16 rows ----------------
#define KPAD 72
__global__ __launch_bounds__(256) void attn_k(const u16* __restrict__ qkv, const u16* __restrict__ vt,
                                              const float* __restrict__ mask, u16* __restrict__ o) {
  __shared__ u16 Ks[64 * KPAD];
  __shared__ u16 Vs[64 * KPAD];
  __shared__ u16 Ps[64 * KPAD];
  const int t = threadIdx.x;
  const int lane = t & 63, wave = t >> 6;
  const int lrow = lane & 15, lgrp = lane >> 4;
  const int qb = blockIdx.x;
  const int bh = blockIdx.y;
  const int b = bh >> 4, hh = bh & 15;

  bf16x8 qf[2];
  const int qrow0 = qb * 64 + wave * 16;
#pragma unroll
  for (int kk = 0; kk < 2; ++kk)
    qf[kk] = *(const bf16x8*)(qkv + (size_t)(b * SEQ + qrow0 + lrow) * 3072 +
                              hh * 64 + kk * 32 + lgrp * 8);

  float mreg[4], lsum[4];
  f32x4 oacc[4];
#pragma unroll
  for (int r = 0; r < 4; ++r) { mreg[r] = -1e30f; lsum[r] = 0.f; }
#pragma unroll
  for (int dn = 0; dn < 4; ++dn) oacc[dn] = (f32x4){0.f, 0.f, 0.f, 0.f};

  const int sr = t >> 3, sc = t & 7;
  for (int it = 0; it < 8; ++it) {
    const int kv0 = it * 64;
#pragma unroll
    for (int half = 0; half < 2; ++half) {
      int r = sr + half * 32;
      uint4 kv4 = *(const uint4*)(qkv + (size_t)(b * SEQ + kv0 + r) * 3072 + 1024 + hh * 64 + sc * 8);
      *(uint4*)(&Ks[r * KPAD + sc * 8]) = kv4;
      uint4 vv4 = *(const uint4*)(vt + (size_t)(bh * 64 + r) * SEQ + kv0 + sc * 8);
      *(uint4*)(&Vs[r * KPAD + sc * 8]) = vv4;
    }
    __syncthreads();

    f32x4 s[4];
#pragma unroll
    for (int nt = 0; nt < 4; ++nt) s[nt] = (f32x4){0.f, 0.f, 0.f, 0.f};
#pragma unroll
    for (int nt = 0; nt < 4; ++nt)
#pragma unroll
      for (int kk = 0; kk < 2; ++kk) {
        bf16x8 kf = *(const bf16x8*)(&Ks[(nt * 16 + lrow) * KPAD + kk * 32 + lgrp * 8]);
        s[nt] = __builtin_amdgcn_mfma_f32_16x16x32_bf16(qf[kk], kf, s[nt], 0, 0, 0);
      }
    float mv[4];
#pragma unroll
    for (int nt = 0; nt < 4; ++nt) mv[nt] = mask[b * SEQ + kv0 + nt * 16 + lrow] * -1e9f;
#pragma unroll
    for (int nt = 0; nt < 4; ++nt)
#pragma unroll
      for (int r = 0; r < 4; ++r) s[nt][r] = s[nt][r] + mv[nt];

#pragma unroll
    for (int r = 0; r < 4; ++r) {
      float mx = fmaxf(fmaxf(s[0][r], s[1][r]), fmaxf(s[2][r], s[3][r]));
      mx = fmaxf(mx, __shfl_xor(mx, 1));
      mx = fmaxf(mx, __shfl_xor(mx, 2));
      mx = fmaxf(mx, __shfl_xor(mx, 4));
      mx = fmaxf(mx, __shfl_xor(mx, 8));
      float mnew = fmaxf(mreg[r], mx);
      float corr = __expf(mreg[r] - mnew);
      mreg[r] = mnew;
      float p0 = __expf(s[0][r] - mnew);
      float p1 = __expf(s[1][r] - mnew);
      float p2 = __expf(s[2][r] - mnew);
      float p3 = __expf(s[3][r] - mnew);
      float rs = p0 + p1 + p2 + p3;
      rs += __shfl_xor(rs, 1);
      rs += __shfl_xor(rs, 2);
      rs += __shfl_xor(rs, 4);
      rs += __shfl_xor(rs, 8);
      lsum[r] = lsum[r] * corr + rs;
#pragma unroll
      for (int dn = 0; dn < 4; ++dn) oacc[dn][r] = oacc[dn][r] * corr;
      int prow = wave * 16 + lgrp * 4 + r;
      Ps[prow * KPAD + 0 + lrow] = f2bf(p0);
      Ps[prow * KPAD + 16 + lrow] = f2bf(p1);
      Ps[prow * KPAD + 32 + lrow] = f2bf(p2);
      Ps[prow * KPAD + 48 + lrow] = f2bf(p3);
    }
    __syncthreads();
#pragma unroll
    for (int kk = 0; kk < 2; ++kk) {
      bf16x8 pf = *(const bf16x8*)(&Ps[(wave * 16 + lrow) * KPAD + kk * 32 + lgrp * 8]);
#pragma unroll
      for (int dn = 0; dn < 4; ++dn) {
        bf16x8 vf = *(const bf16x8*)(&Vs[(dn * 16 + lrow) * KPAD + kk * 32 + lgrp * 8]);
        oacc[dn] = __builtin_amdgcn_mfma_f32_16x16x32_bf16(pf, vf, oacc[dn], 0, 0, 0);
      }
    }
    __syncthreads();
  }
#pragma unroll
  for (int dn = 0; dn < 4; ++dn)
#pragma unroll
    for (int r = 0; r < 4; ++r) {
      int qrow = qrow0 + lgrp * 4 + r;
      o[(size_t)(b * SEQ + qrow) * D_MODEL + hh * 64 + dn * 16 + lrow] =
          f2bf(oacc[dn][r] / lsum[r]);
    }
}

// ---------------- residual + two split-K partials + LayerNorm ----------------
__global__ __launch_bounds__(256) void ln_k(const float* __restrict__ res, const float* __restrict__ p0,
                                            const float* __restrict__ p1, const float* __restrict__ g,
                                            const float* __restrict__ be, float* __restrict__ out,
                                            u16* __restrict__ outb) {
  __shared__ float red[8];
  const int row = blockIdx.x, t = threadIdx.x;
  float4 va = *(const float4*)(res + (size_t)row * D_MODEL + t * 4);
  float4 vb = *(const float4*)(p0 + (size_t)row * D_MODEL + t * 4);
  float4 vc = *(const float4*)(p1 + (size_t)row * D_MODEL + t * 4);
  float x0 = va.x + vb.x + vc.x, x1 = va.y + vb.y + vc.y;
  float x2 = va.z + vb.z + vc.z, x3 = va.w + vb.w + vc.w;
  float s = x0 + x1 + x2 + x3;
  float s2 = x0 * x0 + x1 * x1 + x2 * x2 + x3 * x3;
#pragma unroll
  for (int off = 1; off < 64; off <<= 1) {
    s += __shfl_xor(s, off);
    s2 += __shfl_xor(s2, off);
  }
  const int wave = t >> 6, lane = t & 63;
  if (lane == 0) { red[wave] = s; red[4 + wave] = s2; }
  __syncthreads();
  s = red[0] + red[1] + red[2] + red[3];
  s2 = red[4] + red[5] + red[6] + red[7];
  float mean = s * (1.f / D_MODEL);
  float var = s2 * (1.f / D_MODEL) - mean * mean;
  float inv = rsqrtf(var + 1e-6f);
  float4 vg = *(const float4*)(g + t * 4);
  float4 ve = *(const float4*)(be + t * 4);
  float4 r;
  r.x = (x0 - mean) * inv * vg.x + ve.x;
  r.y = (x1 - mean) * inv * vg.y + ve.y;
  r.z = (x2 - mean) * inv * vg.z + ve.z;
  r.w = (x3 - mean) * inv * vg.w + ve.w;
  *(float4*)(out + (size_t)row * D_MODEL + t * 4) = r;
  if (outb) {
    ushort4 w;
    w.x = f2bf(r.x); w.y = f2bf(r.y); w.z = f2bf(r.z); w.w = f2bf(r.w);
    *(ushort4*)(outb + (size_t)row * D_MODEL + t * 4) = w;
  }
}

// ---------------- launch ----------------
extern "C" void kernel_launch(void* const* d_in, const int* in_sizes, int n_in,
                              void* d_out, int out_size, void* d_ws, size_t ws_size,
                              hipStream_t stream) {
  const float* x = (const float*)d_in[0];
  const float* mask = (const float*)d_in[1];
  const float* Wq = (const float*)d_in[2];
  const float* bq = (const float*)d_in[3];
  const float* Wk = (const float*)d_in[4];
  const float* bk = (const float*)d_in[5];
  const float* Wv = (const float*)d_in[6];
  const float* bv = (const float*)d_in[7];
  const float* Wo = (const float*)d_in[8];
  const float* bo = (const float*)d_in[9];
  const float* W1 = (const float*)d_in[10];
  const float* b1 = (const float*)d_in[11];
  const float* W2 = (const float*)d_in[12];
  const float* b2 = (const float*)d_in[13];
  const float* g1 = (const float*)d_in[14];
  const float* be1 = (const float*)d_in[15];
  const float* g2 = (const float*)d_in[16];
  const float* be2 = (const float*)d_in[17];
  float* out = (float*)d_out;

  const size_t NTOK = (size_t)BATCH * SEQ;  // 2048
  const size_t ACT = NTOK * D_MODEL;        // 2M
  char* w = (char*)d_ws;
  float* h = (float*)w;     w += ACT * 4;
  float* h1 = (float*)w;    w += ACT * 4;
  float* op = (float*)w;    w += ACT * 4 * 2;       // split-K partials (o-proj / ffn2), f32 x2
  u16* hb = (u16*)w;        w += ACT * 2;
  u16* h1b = (u16*)w;       w += ACT * 2;
  u16* qkvb = (u16*)w;      w += NTOK * 3072 * 2;   // fused q|k|v bf16
  u16* vt_ = (u16*)w;       w += ACT * 2;
  u16* obb = (u16*)w;       w += ACT * 2;           // attn out bf16
  u16* tb = (u16*)w;        w += NTOK * FF * 2;     // ffn1 out bf16
  u16* wqkv_all = (u16*)w;  w += (size_t)NLAYER * 3072 * 1024 * 2;
  u16* wo_all = (u16*)w;    w += (size_t)NLAYER * 1024 * 1024 * 2;
  u16* w1_all = (u16*)w;    w += (size_t)NLAYER * 4096 * 1024 * 2;
  u16* w2_all = (u16*)w;    w += (size_t)NLAYER * 1024 * 4096 * 2;
  float* bqkv_all = (float*)w; w += (size_t)NLAYER * 3072 * 4;

  posenc_k<<<(int)NTOK, 256, 0, stream>>>(x, h, hb);
  wconv_qkv_k<<<dim3(16, 16, 18), 256, 0, stream>>>(Wq, Wk, Wv, wqkv_all);
  wconv_gen_k<<<dim3(16, 16, 6), 256, 0, stream>>>(Wo, wo_all, 1024, 1024);
  wconv_gen_k<<<dim3(64, 16, 6), 256, 0, stream>>>(W1, w1_all, 1024, 4096);
  wconv_gen_k<<<dim3(16, 64, 6), 256, 0, stream>>>(W2, w2_all, 4096, 1024);
  bqkv_k<<<72, 256, 0, stream>>>(bq, bk, bv, bqkv_all);

  for (int l = 0; l < NLAYER; ++l) {
    const u16* wqkv_t = wqkv_all + (size_t)l * 3072 * 1024;
    const u16* wo_t = wo_all + (size_t)l * 1024 * 1024;
    const u16* w1_t = w1_all + (size_t)l * 4096 * 1024;
    const u16* w2_t = w2_all + (size_t)l * 1024 * 4096;
    const float* bqkvl = bqkv_all + (size_t)l * 3072;
    const float* bol = bo + (size_t)l * D_MODEL;
    const float* b1l = b1 + (size_t)l * FF;
    const float* b2l = b2 + (size_t)l * D_MODEL;
    const float* g1l = g1 + (size_t)l * D_MODEL;
    const float* be1l = be1 + (size_t)l * D_MODEL;
    const float* g2l = g2 + (size_t)l * D_MODEL;
    const float* be2l = be2 + (size_t)l * D_MODEL;

    gemm64_k<1, 0, 1><<<dim3(48, 32), 256, 0, stream>>>(hb, wqkv_t, bqkvl, qkvb, 3072, 1024);
    vtrans_k<<<dim3(16, 32, 4), 256, 0, stream>>>(qkvb, vt_);
    attn_k<<<dim3(8, 64), 256, 0, stream>>>(qkvb, vt_, mask, obb);
    gemm64_k<0, 0, 2><<<dim3(16, 32, 2), 256, 0, stream>>>(obb, wo_t, bol, op, 1024, 1024);
    ln_k<<<(int)NTOK, 256, 0, stream>>>(h, op, op + ACT, g1l, be1l, h1, h1b);
    gemm64_k<1, 1, 1><<<dim3(64, 32), 256, 0, stream>>>(h1b, w1_t, b1l, tb, 4096, 1024);
    gemm64_k<0, 0, 2><<<dim3(16, 32, 2), 256, 0, stream>>>(tb, w2_t, b2l, op, 1024, 4096);
    ln_k<<<(int)NTOK, 256, 0, stream>>>(h1, op, op + ACT, g2l, be2l, (l == NLAYER - 1) ? out : h, hb);
  }
}

// Round 7
// 1039.343 us; speedup vs baseline: 2.0159x; 1.1190x over previous
//
#include <hip/hip_runtime.h>

typedef __attribute__((ext_vector_type(8))) short bf16x8;
typedef __attribute__((ext_vector_type(4))) float f32x4;
typedef unsigned short u16;

#define D_MODEL 1024
#define SEQ 512
#define BATCH 4
#define NH 16
#define FF 4096
#define NLAYER 6
#define NTOKS 2048

__device__ __forceinline__ u16 f2bf(float f) {
  unsigned int u = __float_as_uint(f);
  u += 0x7fffu + ((u >> 16) & 1u);
  return (u16)(u >> 16);
}

__device__ __forceinline__ void gload16(const void* g, void* lds) {
  __builtin_amdgcn_global_load_lds((const __attribute__((address_space(1))) void*)g,
                                   (__attribute__((address_space(3))) void*)lds, 16, 0, 0);
}

// ---------------- positional encoding ----------------
__global__ __launch_bounds__(256) void posenc_k(const float* __restrict__ x, float* __restrict__ h,
                                                u16* __restrict__ hb) {
  int row = blockIdx.x;
  int s = row & (SEQ - 1);
  int t = threadIdx.x;
  float4 v = *(const float4*)(x + (size_t)row * D_MODEL + t * 4);
  float r[4] = {v.x, v.y, v.z, v.w};
#pragma unroll
  for (int j = 0; j < 4; ++j) {
    int d = t * 4 + j;
    int p = d >> 1;
    float ang = (float)s * exp2f((float)p * (-2.0f / 1024.0f) * 13.287712379549449f);
    r[j] += (d & 1) ? cosf(ang) : sinf(ang);
  }
  float4 o = {r[0], r[1], r[2], r[3]};
  *(float4*)(h + (size_t)row * D_MODEL + t * 4) = o;
  ushort4 ob;
  ob.x = f2bf(r[0]); ob.y = f2bf(r[1]); ob.z = f2bf(r[2]); ob.w = f2bf(r[3]);
  *(ushort4*)(hb + (size_t)row * D_MODEL + t * 4) = ob;
}

// ---------------- weight transpose+convert ----------------
#define WTP 72
__device__ __forceinline__ void wconv_body(const float* __restrict__ src, u16* __restrict__ dst,
                                           int K, int N, float scale, int nb, int kb) {
  __shared__ u16 tile[64 * WTP];
  const int t = threadIdx.x;
#pragma unroll
  for (int rr = 0; rr < 4; ++rr) {
    int k = (t >> 4) + rr * 16;
    int n4 = (t & 15) * 4;
    float4 v = *(const float4*)(src + (size_t)(kb + k) * N + nb + n4);
    tile[(n4 + 0) * WTP + k] = f2bf(v.x * scale);
    tile[(n4 + 1) * WTP + k] = f2bf(v.y * scale);
    tile[(n4 + 2) * WTP + k] = f2bf(v.z * scale);
    tile[(n4 + 3) * WTP + k] = f2bf(v.w * scale);
  }
  __syncthreads();
#pragma unroll
  for (int rr = 0; rr < 2; ++rr) {
    int n = (t >> 3) + rr * 32;
    int kq = (t & 7) * 8;
    uint4 v = *(const uint4*)&tile[n * WTP + kq];
    *(uint4*)&dst[(size_t)(nb + n) * K + kb + kq] = v;
  }
}

__global__ __launch_bounds__(256) void wconv_qkv_k(const float* __restrict__ Wq,
                                                   const float* __restrict__ Wk,
                                                   const float* __restrict__ Wv,
                                                   u16* __restrict__ dst) {
  int z = blockIdx.z, l = z / 3, which = z % 3;
  const float* src = (which == 0 ? Wq : which == 1 ? Wk : Wv) + (size_t)l * 1024 * 1024;
  u16* d = dst + (size_t)l * 3072 * 1024 + (size_t)which * 1024 * 1024;
  float scale = (which == 0) ? 0.125f : 1.0f;
  wconv_body(src, d, 1024, 1024, scale, blockIdx.x * 64, blockIdx.y * 64);
}

__global__ __launch_bounds__(256) void wconv_gen_k(const float* __restrict__ W, u16* __restrict__ dst,
                                                   int K, int N) {
  int z = blockIdx.z;
  wconv_body(W + (size_t)z * K * N, dst + (size_t)z * N * K, K, N, 1.0f,
             blockIdx.x * 64, blockIdx.y * 64);
}

__global__ __launch_bounds__(256) void bqkv_k(const float* bq, const float* bk, const float* bv,
                                              float* o) {
  int i = blockIdx.x * 256 + threadIdx.x;  // 18432
  int l = i / 3072, j = i % 3072;
  float v = (j < 1024) ? bq[l * 1024 + j] * 0.125f
                       : (j < 2048 ? bk[l * 1024 + j - 1024] : bv[l * 1024 + j - 2048]);
  o[i] = v;
}

// ---------------- GEMM 128x128x32, 4 waves, 4-buf depth-3 vmcnt pipeline, LDS swizzle ----------------
// Swizzle: LDS tile [128 rows][4 slots of 16B]. Stored slot c_st holds global slot
// c_st ^ ((row>>1)&3). Linear LDS dest (global_load_lds), permuted SOURCE, same XOR on read.
// Reads: 16 lanes/column-slice -> 2-way bank alias only (free).
template <int OBF, int RELU, int KSPLIT>
__global__ __launch_bounds__(256) void gemm128_k(const u16* __restrict__ A, const u16* __restrict__ Bt,
                                                 const float* __restrict__ bias, void* __restrict__ Cv,
                                                 int N, int K) {
  __shared__ u16 As[4][128 * 32];
  __shared__ u16 Bs[4][128 * 32];
  const int t = threadIdx.x, lane = t & 63, wave = t >> 6;
  const int wm = wave >> 1, wn = wave & 1;
  const int lrow = lane & 15, lgrp = lane >> 4;

  // bijective XCD-chunk swizzle (GY=16 fixed): consecutive logical ids share bx (weight panel)
  const int GX = N >> 7;
  const int nwg = GX * 16;
  int flat = blockIdx.y * GX + blockIdx.x;  // hw dispatch order (x fastest)
  int q = nwg >> 3, r = nwg & 7, xcd = flat & 7, pos = flat >> 3;
  int logical = (xcd < r ? xcd * (q + 1) : r * (q + 1) + (xcd - r) * q) + pos;
  const int m0 = (logical & 15) * 128, n0 = (logical >> 4) * 128;

  const int kseg = K / KSPLIT;
  const int koff = (KSPLIT > 1) ? blockIdx.z * kseg : 0;

  f32x4 acc[4][4];
#pragma unroll
  for (int i = 0; i < 4; ++i)
#pragma unroll
    for (int j = 0; j < 4; ++j) acc[i][j] = (f32x4){0.f, 0.f, 0.f, 0.f};

  const u16* Ag = A + (size_t)m0 * K + koff;
  const u16* Bg = Bt + (size_t)n0 * K + koff;

  auto stage = [&](int buf, int k0) {
#pragma unroll
    for (int rr = 0; rr < 2; ++rr) {
      int s = rr * 256 + t;                    // 16B slot index (512/tile)
      int row = s >> 2, cst = s & 3;
      int csrc = cst ^ ((row >> 1) & 3);       // inverse-swizzled global source
      gload16(Ag + (size_t)row * K + k0 + csrc * 8, &As[buf][s * 8]);
    }
#pragma unroll
    for (int rr = 0; rr < 2; ++rr) {
      int s = rr * 256 + t;
      int row = s >> 2, cst = s & 3;
      int csrc = cst ^ ((row >> 1) & 3);
      gload16(Bg + (size_t)row * K + k0 + csrc * 8, &Bs[buf][s * 8]);
    }
  };

  const int nk = kseg / 32;
  stage(0, 0);
  stage(1, 32);
  stage(2, 64);
  for (int tt = 0; tt < nk; ++tt) {
    if (tt + 2 < nk) asm volatile("s_waitcnt vmcnt(8)" ::: "memory");
    else if (tt + 1 < nk) asm volatile("s_waitcnt vmcnt(4)" ::: "memory");
    else asm volatile("s_waitcnt vmcnt(0)" ::: "memory");
    __builtin_amdgcn_s_barrier();
    __builtin_amdgcn_sched_barrier(0);
    if (tt + 3 < nk) stage((tt + 3) & 3, (tt + 3) * 32);
    const int cur = tt & 3;
    bf16x8 af[4], bfr[4];
#pragma unroll
    for (int i = 0; i < 4; ++i) {
      int row = wm * 64 + i * 16 + lrow;
      int sl = lgrp ^ ((row >> 1) & 3);
      af[i] = *(const bf16x8*)&As[cur][row * 32 + sl * 8];
    }
#pragma unroll
    for (int j = 0; j < 4; ++j) {
      int row = wn * 64 + j * 16 + lrow;
      int sl = lgrp ^ ((row >> 1) & 3);
      bfr[j] = *(const bf16x8*)&Bs[cur][row * 32 + sl * 8];
    }
    __builtin_amdgcn_s_setprio(1);
#pragma unroll
    for (int i = 0; i < 4; ++i)
#pragma unroll
      for (int j = 0; j < 4; ++j)
        acc[i][j] = __builtin_amdgcn_mfma_f32_16x16x32_bf16(af[i], bfr[j], acc[i][j], 0, 0, 0);
    __builtin_amdgcn_s_setprio(0);
  }

  const size_t outoff = (KSPLIT > 1) ? (size_t)blockIdx.z * NTOKS * N : 0;
#pragma unroll
  for (int j = 0; j < 4; ++j) {
    int col = n0 + wn * 64 + j * 16 + lrow;
    float bv = (KSPLIT == 1 || blockIdx.z == 0) ? bias[col] : 0.f;
#pragma unroll
    for (int i = 0; i < 4; ++i) {
      int rowb = m0 + wm * 64 + i * 16 + lgrp * 4;
#pragma unroll
      for (int r = 0; r < 4; ++r) {
        float v = acc[i][j][r] + bv;
        if (RELU) v = fmaxf(v, 0.f);
        if (OBF)
          ((u16*)Cv)[(size_t)(rowb + r) * N + col] = f2bf(v);
        else
          ((float*)Cv)[outoff + (size_t)(rowb + r) * N + col] = v;
      }
    }
  }
}

// ---------------- V transpose from fused qkv ----------------
__global__ __launch_bounds__(256) void vtrans_k(const u16* __restrict__ qkv, u16* __restrict__ vt) {
  __shared__ u16 tile[32][33];
  const int bx = blockIdx.x, by = blockIdx.y, b = blockIdx.z;
  const int tx = threadIdx.x & 31, ty = threadIdx.x >> 5;
#pragma unroll
  for (int i = 0; i < 32; i += 8) {
    int sidx = bx * 32 + ty + i, d = by * 32 + tx;
    tile[ty + i][tx] = qkv[(size_t)(b * SEQ + sidx) * 3072 + 2048 + d];
  }
  __syncthreads();
#pragma unroll
  for (int i = 0; i < 32; i += 8) {
    int d = by * 32 + ty + i, sidx = bx * 32 + tx;
    vt[(size_t)(b * D_MODEL + d) * SEQ + sidx] = tile[tx][ty + i];
  }
}

// ---------------- fused flash attention: 64 q-rows/block ----------------
#define KPAD 72
__global__ __launch_bounds__(256) void attn_k(const u16* __restrict__ qkv, const u16* __restrict__ vt,
                                              const float* __restrict__ mask, u16* __restrict__ o) {
  __shared__ u16 Ks[64 * KPAD];
  __shared__ u16 Vs[64 * KPAD];
  __shared__ u16 Ps[64 * KPAD];
  const int t = threadIdx.x;
  const int lane = t & 63, wave = t >> 6;
  const int lrow = lane & 15, lgrp = lane >> 4;
  const int qb = blockIdx.x;
  const int bh = blockIdx.y;
  const int b = bh >> 4, hh = bh & 15;

  bf16x8 qf[2];
  const int qrow0 = qb * 64 + wave * 16;
#pragma unroll
  for (int kk = 0; kk < 2; ++kk)
    qf[kk] = *(const bf16x8*)(qkv + (size_t)(b * SEQ + qrow0 + lrow) * 3072 +
                              hh * 64 + kk * 32 + lgrp * 8);

  float mreg[4], lsum[4];
  f32x4 oacc[4];
#pragma unroll
  for (int r = 0; r < 4; ++r) { mreg[r] = -1e30f; lsum[r] = 0.f; }
#pragma unroll
  for (int dn = 0; dn < 4; ++dn) oacc[dn] = (f32x4){0.f, 0.f, 0.f, 0.f};

  const int sr = t >> 3, sc = t & 7;
  for (int it = 0; it < 8; ++it) {
    const int kv0 = it * 64;
#pragma unroll
    for (int half = 0; half < 2; ++half) {
      int r = sr + half * 32;
      uint4 kv4 = *(const uint4*)(qkv + (size_t)(b * SEQ + kv0 + r) * 3072 + 1024 + hh * 64 + sc * 8);
      *(uint4*)(&Ks[r * KPAD + sc * 8]) = kv4;
      uint4 vv4 = *(const uint4*)(vt + (size_t)(bh * 64 + r) * SEQ + kv0 + sc * 8);
      *(uint4*)(&Vs[r * KPAD + sc * 8]) = vv4;
    }
    __syncthreads();

    f32x4 s[4];
#pragma unroll
    for (int nt = 0; nt < 4; ++nt) s[nt] = (f32x4){0.f, 0.f, 0.f, 0.f};
    __builtin_amdgcn_s_setprio(1);
#pragma unroll
    for (int nt = 0; nt < 4; ++nt)
#pragma unroll
      for (int kk = 0; kk < 2; ++kk) {
        bf16x8 kf = *(const bf16x8*)(&Ks[(nt * 16 + lrow) * KPAD + kk * 32 + lgrp * 8]);
        s[nt] = __builtin_amdgcn_mfma_f32_16x16x32_bf16(qf[kk], kf, s[nt], 0, 0, 0);
      }
    __builtin_amdgcn_s_setprio(0);
    float mv[4];
#pragma unroll
    for (int nt = 0; nt < 4; ++nt) mv[nt] = mask[b * SEQ + kv0 + nt * 16 + lrow] * -1e9f;
#pragma unroll
    for (int nt = 0; nt < 4; ++nt)
#pragma unroll
      for (int r = 0; r < 4; ++r) s[nt][r] = s[nt][r] + mv[nt];

#pragma unroll
    for (int r = 0; r < 4; ++r) {
      float mx = fmaxf(fmaxf(s[0][r], s[1][r]), fmaxf(s[2][r], s[3][r]));
      mx = fmaxf(mx, __shfl_xor(mx, 1));
      mx = fmaxf(mx, __shfl_xor(mx, 2));
      mx = fmaxf(mx, __shfl_xor(mx, 4));
      mx = fmaxf(mx, __shfl_xor(mx, 8));
      float mnew = fmaxf(mreg[r], mx);
      float corr = __expf(mreg[r] - mnew);
      mreg[r] = mnew;
      float p0 = __expf(s[0][r] - mnew);
      float p1 = __expf(s[1][r] - mnew);
      float p2 = __expf(s[2][r] - mnew);
      float p3 = __expf(s[3][r] - mnew);
      float rs = p0 + p1 + p2 + p3;
      rs += __shfl_xor(rs, 1);
      rs += __shfl_xor(rs, 2);
      rs += __shfl_xor(rs, 4);
      rs += __shfl_xor(rs, 8);
      lsum[r] = lsum[r] * corr + rs;
#pragma unroll
      for (int dn = 0; dn < 4; ++dn) oacc[dn][r] = oacc[dn][r] * corr;
      int prow = wave * 16 + lgrp * 4 + r;
      Ps[prow * KPAD + 0 + lrow] = f2bf(p0);
      Ps[prow * KPAD + 16 + lrow] = f2bf(p1);
      Ps[prow * KPAD + 32 + lrow] = f2bf(p2);
      Ps[prow * KPAD + 48 + lrow] = f2bf(p3);
    }
    __syncthreads();
    __builtin_amdgcn_s_setprio(1);
#pragma unroll
    for (int kk = 0; kk < 2; ++kk) {
      bf16x8 pf = *(const bf16x8*)(&Ps[(wave * 16 + lrow) * KPAD + kk * 32 + lgrp * 8]);
#pragma unroll
      for (int dn = 0; dn < 4; ++dn) {
        bf16x8 vf = *(const bf16x8*)(&Vs[(dn * 16 + lrow) * KPAD + kk * 32 + lgrp * 8]);
        oacc[dn] = __builtin_amdgcn_mfma_f32_16x16x32_bf16(pf, vf, oacc[dn], 0, 0, 0);
      }
    }
    __builtin_amdgcn_s_setprio(0);
    __syncthreads();
  }
#pragma unroll
  for (int dn = 0; dn < 4; ++dn)
#pragma unroll
    for (int r = 0; r < 4; ++r) {
      int qrow = qrow0 + lgrp * 4 + r;
      o[(size_t)(b * SEQ + qrow) * D_MODEL + hh * 64 + dn * 16 + lrow] =
          f2bf(oacc[dn][r] / lsum[r]);
    }
}

// ---------------- residual + P split-K partials + LayerNorm ----------------
template <int P>
__global__ __launch_bounds__(256) void ln_k(const float* __restrict__ res, const float* __restrict__ parts,
                                            const float* __restrict__ g, const float* __restrict__ be,
                                            float* __restrict__ out, u16* __restrict__ outb) {
  __shared__ float red[8];
  const int row = blockIdx.x, t = threadIdx.x;
  float4 va = *(const float4*)(res + (size_t)row * D_MODEL + t * 4);
  float x0 = va.x, x1 = va.y, x2 = va.z, x3 = va.w;
#pragma unroll
  for (int p = 0; p < P; ++p) {
    float4 vp = *(const float4*)(parts + (size_t)p * NTOKS * D_MODEL + (size_t)row * D_MODEL + t * 4);
    x0 += vp.x; x1 += vp.y; x2 += vp.z; x3 += vp.w;
  }
  float s = x0 + x1 + x2 + x3;
  float s2 = x0 * x0 + x1 * x1 + x2 * x2 + x3 * x3;
#pragma unroll
  for (int off = 1; off < 64; off <<= 1) {
    s += __shfl_xor(s, off);
    s2 += __shfl_xor(s2, off);
  }
  const int wave = t >> 6, lane = t & 63;
  if (lane == 0) { red[wave] = s; red[4 + wave] = s2; }
  __syncthreads();
  s = red[0] + red[1] + red[2] + red[3];
  s2 = red[4] + red[5] + red[6] + red[7];
  float mean = s * (1.f / D_MODEL);
  float var = s2 * (1.f / D_MODEL) - mean * mean;
  float inv = rsqrtf(var + 1e-6f);
  float4 vg = *(const float4*)(g + t * 4);
  float4 ve = *(const float4*)(be + t * 4);
  float4 r;
  r.x = (x0 - mean) * inv * vg.x + ve.x;
  r.y = (x1 - mean) * inv * vg.y + ve.y;
  r.z = (x2 - mean) * inv * vg.z + ve.z;
  r.w = (x3 - mean) * inv * vg.w + ve.w;
  *(float4*)(out + (size_t)row * D_MODEL + t * 4) = r;
  if (outb) {
    ushort4 w;
    w.x = f2bf(r.x); w.y = f2bf(r.y); w.z = f2bf(r.z); w.w = f2bf(r.w);
    *(ushort4*)(outb + (size_t)row * D_MODEL + t * 4) = w;
  }
}

// ---------------- launch ----------------
extern "C" void kernel_launch(void* const* d_in, const int* in_sizes, int n_in,
                              void* d_out, int out_size, void* d_ws, size_t ws_size,
                              hipStream_t stream) {
  const float* x = (const float*)d_in[0];
  const float* mask = (const float*)d_in[1];
  const float* Wq = (const float*)d_in[2];
  const float* bq = (const float*)d_in[3];
  const float* Wk = (const float*)d_in[4];
  const float* bk = (const float*)d_in[5];
  const float* Wv = (const float*)d_in[6];
  const float* bv = (const float*)d_in[7];
  const float* Wo = (const float*)d_in[8];
  const float* bo = (const float*)d_in[9];
  const float* W1 = (const float*)d_in[10];
  const float* b1 = (const float*)d_in[11];
  const float* W2 = (const float*)d_in[12];
  const float* b2 = (const float*)d_in[13];
  const float* g1 = (const float*)d_in[14];
  const float* be1 = (const float*)d_in[15];
  const float* g2 = (const float*)d_in[16];
  const float* be2 = (const float*)d_in[17];
  float* out = (float*)d_out;

  const size_t NTOK = (size_t)BATCH * SEQ;  // 2048
  const size_t ACT = NTOK * D_MODEL;        // 2M
  char* w = (char*)d_ws;
  float* h = (float*)w;     w += ACT * 4;
  float* h1 = (float*)w;    w += ACT * 4;
  float* op = (float*)w;    w += ACT * 4 * 4;       // split-K partials x4 (f32)
  u16* hb = (u16*)w;        w += ACT * 2;
  u16* h1b = (u16*)w;       w += ACT * 2;
  u16* qkvb = (u16*)w;      w += NTOK * 3072 * 2;
  u16* vt_ = (u16*)w;       w += ACT * 2;
  u16* obb = (u16*)w;       w += ACT * 2;
  u16* tb = (u16*)w;        w += NTOK * FF * 2;
  u16* wqkv_all = (u16*)w;  w += (size_t)NLAYER * 3072 * 1024 * 2;
  u16* wo_all = (u16*)w;    w += (size_t)NLAYER * 1024 * 1024 * 2;
  u16* w1_all = (u16*)w;    w += (size_t)NLAYER * 4096 * 1024 * 2;
  u16* w2_all = (u16*)w;    w += (size_t)NLAYER * 1024 * 4096 * 2;
  float* bqkv_all = (float*)w; w += (size_t)NLAYER * 3072 * 4;

  posenc_k<<<(int)NTOK, 256, 0, stream>>>(x, h, hb);
  wconv_qkv_k<<<dim3(16, 16, 18), 256, 0, stream>>>(Wq, Wk, Wv, wqkv_all);
  wconv_gen_k<<<dim3(16, 16, 6), 256, 0, stream>>>(Wo, wo_all, 1024, 1024);
  wconv_gen_k<<<dim3(64, 16, 6), 256, 0, stream>>>(W1, w1_all, 1024, 4096);
  wconv_gen_k<<<dim3(16, 64, 6), 256, 0, stream>>>(W2, w2_all, 4096, 1024);
  bqkv_k<<<72, 256, 0, stream>>>(bq, bk, bv, bqkv_all);

  for (int l = 0; l < NLAYER; ++l) {
    const u16* wqkv_t = wqkv_all + (size_t)l * 3072 * 1024;
    const u16* wo_t = wo_all + (size_t)l * 1024 * 1024;
    const u16* w1_t = w1_all + (size_t)l * 4096 * 1024;
    const u16* w2_t = w2_all + (size_t)l * 1024 * 4096;
    const float* bqkvl = bqkv_all + (size_t)l * 3072;
    const float* bol = bo + (size_t)l * D_MODEL;
    const float* b1l = b1 + (size_t)l * FF;
    const float* b2l = b2 + (size_t)l * D_MODEL;
    const float* g1l = g1 + (size_t)l * D_MODEL;
    const float* be1l = be1 + (size_t)l * D_MODEL;
    const float* g2l = g2 + (size_t)l * D_MODEL;
    const float* be2l = be2 + (size_t)l * D_MODEL;

    gemm128_k<1, 0, 1><<<dim3(24, 16), 256, 0, stream>>>(hb, wqkv_t, bqkvl, qkvb, 3072, 1024);
    vtrans_k<<<dim3(16, 32, 4), 256, 0, stream>>>(qkvb, vt_);
    attn_k<<<dim3(8, 64), 256, 0, stream>>>(qkvb, vt_, mask, obb);
    gemm128_k<0, 0, 4><<<dim3(8, 16, 4), 256, 0, stream>>>(obb, wo_t, bol, op, 1024, 1024);
    ln_k<4><<<(int)NTOK, 256, 0, stream>>>(h, op, g1l, be1l, h1, h1b);
    gemm128_k<1, 1, 1><<<dim3(32, 16), 256, 0, stream>>>(h1b, w1_t, b1l, tb, 4096, 1024);
    gemm128_k<0, 0, 4><<<dim3(8, 16, 4), 256, 0, stream>>>(tb, w2_t, b2l, op, 1024, 4096);
    ln_k<4><<<(int)NTOK, 256, 0, stream>>>(h1, op, g2l, be2l, (l == NLAYER - 1) ? out : h, hb);
  }
}